// Round 2
// baseline (12924.959 us; speedup 1.0000x reference)
//
#include <hip/hip_runtime.h>
#include <hip/hip_bf16.h>
#include <stdint.h>

#define B_ 2
#define S_ 4096
#define D_ 768
#define H_ 12
#define DH_ 64
#define L_ 2
#define W_ 256
#define G_ 64
#define FF_ 3072
#define C_ 7
#define SEP_ 2
#define NEG_ (-1000000000.0f)

// internal bf16 helpers (only for OUR scratch buffers; all external I/O is fp32)
__device__ __forceinline__ float bfu2f(unsigned short u) {
    return __uint_as_float(((unsigned int)u) << 16);
}
__device__ __forceinline__ float bflo(unsigned int u) { return __uint_as_float(u << 16); }
__device__ __forceinline__ float bfhi(unsigned int u) { return __uint_as_float(u & 0xffff0000u); }
__device__ __forceinline__ unsigned short f2bfu(float f) {
    unsigned int x = __float_as_uint(f);
    unsigned int r = (x + 0x7fffu + ((x >> 16) & 1u)) >> 16;
    return (unsigned short)r;
}
__device__ __forceinline__ float gelu_tanh(float v) {
    float c = 0.7978845608028654f * (v + 0.044715f * v * v * v);
    return 0.5f * v * (1.0f + tanhf(c));
}

// dot of 64-float LDS q vector with 64 internal-bf16 (contiguous, 16B-aligned)
__device__ __forceinline__ float dot64q(const float* __restrict__ qv,
                                        const unsigned short* __restrict__ kr) {
    const uint4* k4 = (const uint4*)kr;
    float acc = 0.f;
#pragma unroll
    for (int i = 0; i < 8; i++) {
        uint4 u = k4[i];
        acc += qv[i * 8 + 0] * bflo(u.x); acc += qv[i * 8 + 1] * bfhi(u.x);
        acc += qv[i * 8 + 2] * bflo(u.y); acc += qv[i * 8 + 3] * bfhi(u.y);
        acc += qv[i * 8 + 4] * bflo(u.z); acc += qv[i * 8 + 5] * bfhi(u.z);
        acc += qv[i * 8 + 6] * bflo(u.w); acc += qv[i * 8 + 7] * bfhi(u.w);
    }
    return acc;
}

// ---------------- embedding + LN ----------------
__global__ __launch_bounds__(256) void k_embed_ln(
    const int* __restrict__ ids, const float* __restrict__ etok,
    const float* __restrict__ epos, const float* __restrict__ lns,
    const float* __restrict__ lnb, float* __restrict__ x) {
    int row = blockIdx.x;           // b*S + s
    int s = row & (S_ - 1);
    int t = threadIdx.x;
    __shared__ float xr[D_];
    __shared__ float red[256];
    int id = ids[row];
    float loc = 0.f;
    for (int d = t; d < D_; d += 256) {
        float v = etok[(size_t)id * D_ + d] + epos[(size_t)s * D_ + d];
        xr[d] = v; loc += v;
    }
    red[t] = loc; __syncthreads();
    for (int o = 128; o; o >>= 1) { if (t < o) red[t] += red[t + o]; __syncthreads(); }
    float mean = red[0] * (1.0f / D_);
    __syncthreads();
    loc = 0.f;
    for (int d = t; d < D_; d += 256) { float dd = xr[d] - mean; loc += dd * dd; }
    red[t] = loc; __syncthreads();
    for (int o = 128; o; o >>= 1) { if (t < o) red[t] += red[t + o]; __syncthreads(); }
    float rs = rsqrtf(red[0] * (1.0f / D_) + 1e-5f);
    for (int d = t; d < D_; d += 256)
        x[(size_t)row * D_ + d] = (xr[d] - mean) * rs * lns[d] + lnb[d];
}

// ---------------- residual add + LN (in-place on x) ----------------
__global__ __launch_bounds__(256) void k_add_ln(
    float* __restrict__ x, const float* __restrict__ y,
    const float* __restrict__ lns, const float* __restrict__ lnb) {
    int row = blockIdx.x;
    int t = threadIdx.x;
    __shared__ float xr[D_];
    __shared__ float red[256];
    float loc = 0.f;
    for (int d = t; d < D_; d += 256) {
        float v = x[(size_t)row * D_ + d] + y[(size_t)row * D_ + d];
        xr[d] = v; loc += v;
    }
    red[t] = loc; __syncthreads();
    for (int o = 128; o; o >>= 1) { if (t < o) red[t] += red[t + o]; __syncthreads(); }
    float mean = red[0] * (1.0f / D_);
    __syncthreads();
    loc = 0.f;
    for (int d = t; d < D_; d += 256) { float dd = xr[d] - mean; loc += dd * dd; }
    red[t] = loc; __syncthreads();
    for (int o = 128; o; o >>= 1) { if (t < o) red[t] += red[t + o]; __syncthreads(); }
    float rs = rsqrtf(red[0] * (1.0f / D_) + 1e-5f);
    for (int d = t; d < D_; d += 256)
        x[(size_t)row * D_ + d] = (xr[d] - mean) * rs * lns[d] + lnb[d];
}

// ---------------- global-token index extraction ----------------
__global__ void k_idx(const int* __restrict__ ids, int* __restrict__ idxg) {
    int b = threadIdx.x;
    if (b >= B_) return;
    int cnt = 0;
    for (int s = 0; s < S_; s++) {
        if (ids[b * S_ + s] == SEP_ || s == 0) {
            if (cnt < G_) idxg[b * G_ + cnt] = s;
            cnt++;
        }
    }
    for (; cnt < G_; cnt++) idxg[b * G_ + cnt] = 0;
}

// ---------------- GEMM: C[M,N] = A[M,K](f32) @ Bw[K,N](f32) + bias(f32) ----------------
// M,N multiples of 64; K multiple of 16. act=1 -> gelu. One of Cf/Cb non-null.
__global__ __launch_bounds__(256) void k_gemm(
    const float* __restrict__ A, const float* __restrict__ Bw,
    const float* __restrict__ bias, float* __restrict__ Cf,
    unsigned short* __restrict__ Cb, int M, int N, int K, int act) {
    __shared__ float As[16][68];
    __shared__ float Bs[16][68];
    int tl = threadIdx.x;
    int tx = tl & 15, ty = tl >> 4;
    int m0 = blockIdx.y << 6, n0 = blockIdx.x << 6;
    float c[4][4] = {{0.f}};
    int arow = tl >> 2, akk = (tl & 3) << 2;
    int bkk = tl >> 4, bcol = (tl & 15) << 2;
    for (int k0 = 0; k0 < K; k0 += 16) {
        float4 a4 = *(const float4*)(A + (size_t)(m0 + arow) * K + k0 + akk);
        As[akk + 0][arow] = a4.x; As[akk + 1][arow] = a4.y;
        As[akk + 2][arow] = a4.z; As[akk + 3][arow] = a4.w;
        float4 b4 = *(const float4*)(Bw + (size_t)(k0 + bkk) * N + n0 + bcol);
        Bs[bkk][bcol + 0] = b4.x; Bs[bkk][bcol + 1] = b4.y;
        Bs[bkk][bcol + 2] = b4.z; Bs[bkk][bcol + 3] = b4.w;
        __syncthreads();
#pragma unroll
        for (int kk = 0; kk < 16; kk++) {
            float4 av = *(const float4*)&As[kk][ty << 2];
            float4 bv = *(const float4*)&Bs[kk][tx << 2];
            float aa[4] = {av.x, av.y, av.z, av.w};
            float bb[4] = {bv.x, bv.y, bv.z, bv.w};
#pragma unroll
            for (int i = 0; i < 4; i++)
#pragma unroll
                for (int j = 0; j < 4; j++) c[i][j] += aa[i] * bb[j];
        }
        __syncthreads();
    }
    float bias4[4];
#pragma unroll
    for (int j = 0; j < 4; j++) bias4[j] = bias[n0 + (tx << 2) + j];
#pragma unroll
    for (int i = 0; i < 4; i++) {
        int mrow = m0 + (ty << 2) + i;
        float v0 = c[i][0] + bias4[0], v1 = c[i][1] + bias4[1];
        float v2 = c[i][2] + bias4[2], v3 = c[i][3] + bias4[3];
        if (act) { v0 = gelu_tanh(v0); v1 = gelu_tanh(v1); v2 = gelu_tanh(v2); v3 = gelu_tanh(v3); }
        if (Cf) {
            float4 o; o.x = v0; o.y = v1; o.z = v2; o.w = v3;
            *(float4*)(Cf + (size_t)mrow * N + n0 + (tx << 2)) = o;
        } else {
            ushort4 o; o.x = f2bfu(v0); o.y = f2bfu(v1); o.z = f2bfu(v2); o.w = f2bfu(v3);
            *(ushort4*)(Cb + (size_t)mrow * N + n0 + (tx << 2)) = o;
        }
    }
}

// ---------------- local (banded + global-key) attention, one block per (s,h,b) ----------------
__global__ __launch_bounds__(256) void k_local_attn(
    const unsigned short* __restrict__ q, const unsigned short* __restrict__ k,
    const unsigned short* __restrict__ v, const int* __restrict__ ids,
    const int* __restrict__ am, const int* __restrict__ idxg,
    float* __restrict__ outT) {
    int s = blockIdx.x, h = blockIdx.y, b = blockIdx.z;
    int t = threadIdx.x;
    __shared__ float qv[DH_];
    __shared__ float sc[832];
    __shared__ float red[256];
    __shared__ float part[4][DH_];
    const size_t rowbase = ((size_t)(b * S_ + s)) * D_ + h * DH_;
    if (t < DH_) qv[t] = bfu2f(q[rowbase + t]);
    __syncthreads();
    int qi = s & (W_ - 1);
    int base = (s & ~(W_ - 1)) - W_;
    for (int j = t; j < 832; j += 256) {
        float sv = NEG_;
        int kp; bool ok;
        if (j < 768) {
            kp = base + j;
            ok = (j >= qi) && (j <= qi + 2 * W_) && (kp >= 0) && (kp < S_);
            if (ok) ok = (am[b * S_ + kp] != 0) && !(ids[b * S_ + kp] == SEP_ || kp == 0);
        } else {
            kp = idxg[b * G_ + (j - 768)];
            ok = true;
        }
        if (ok) sv = dot64q(qv, k + ((size_t)(b * S_ + kp)) * D_ + h * DH_) * 0.125f;
        sc[j] = sv;
    }
    __syncthreads();
    float lm = -3.4e38f;
    for (int j = t; j < 832; j += 256) lm = fmaxf(lm, sc[j]);
    red[t] = lm; __syncthreads();
    for (int o = 128; o; o >>= 1) { if (t < o) red[t] = fmaxf(red[t], red[t + o]); __syncthreads(); }
    float mx = red[0];
    __syncthreads();
    float ls = 0.f;
    for (int j = t; j < 832; j += 256) { float e = __expf(sc[j] - mx); sc[j] = e; ls += e; }
    red[t] = ls; __syncthreads();
    for (int o = 128; o; o >>= 1) { if (t < o) red[t] += red[t + o]; __syncthreads(); }
    float inv = 1.0f / red[0];
    __syncthreads();
    int d = t & 63, cch = t >> 6;
    float acc = 0.f;
    for (int j = cch; j < 832; j += 4) {
        float p = sc[j];
        if (p > 0.f) {
            int kp = (j < 768) ? (base + j) : idxg[b * G_ + (j - 768)];
            acc += p * bfu2f(v[((size_t)(b * S_ + kp)) * D_ + h * DH_ + d]);
        }
    }
    part[cch][d] = acc;
    __syncthreads();
    if (t < DH_)
        outT[rowbase + t] = (part[0][t] + part[1][t] + part[2][t] + part[3][t]) * inv;
}

// ---------------- global-query full attention, one block per (g,h,b); writes into outT rows ----------------
__global__ __launch_bounds__(256) void k_glob_attn(
    const unsigned short* __restrict__ qg, const unsigned short* __restrict__ kga,
    const unsigned short* __restrict__ vga, const int* __restrict__ am,
    const int* __restrict__ idxg, float* __restrict__ outT) {
    int g = blockIdx.x, h = blockIdx.y, b = blockIdx.z;
    int t = threadIdx.x;
    __shared__ float qv[DH_];
    __shared__ float sc[S_];
    __shared__ float red[256];
    __shared__ float part[4][DH_];
    if (t < DH_) qv[t] = bfu2f(qg[((size_t)(b * G_ + g)) * D_ + h * DH_ + t]);
    __syncthreads();
    for (int j = t; j < S_; j += 256) {
        float sv = NEG_;
        if (am[b * S_ + j] != 0)
            sv = dot64q(qv, kga + ((size_t)(b * S_ + j)) * D_ + h * DH_) * 0.125f;
        sc[j] = sv;
    }
    __syncthreads();
    float lm = -3.4e38f;
    for (int j = t; j < S_; j += 256) lm = fmaxf(lm, sc[j]);
    red[t] = lm; __syncthreads();
    for (int o = 128; o; o >>= 1) { if (t < o) red[t] = fmaxf(red[t], red[t + o]); __syncthreads(); }
    float mx = red[0];
    __syncthreads();
    float ls = 0.f;
    for (int j = t; j < S_; j += 256) { float e = __expf(sc[j] - mx); sc[j] = e; ls += e; }
    red[t] = ls; __syncthreads();
    for (int o = 128; o; o >>= 1) { if (t < o) red[t] += red[t + o]; __syncthreads(); }
    float inv = 1.0f / red[0];
    __syncthreads();
    int d = t & 63, cch = t >> 6;
    float acc = 0.f;
    for (int j = cch; j < S_; j += 4)
        acc += sc[j] * bfu2f(vga[((size_t)(b * S_ + j)) * D_ + h * DH_ + d]);
    part[cch][d] = acc;
    __syncthreads();
    if (t < DH_) {
        int srow = idxg[b * G_ + g];
        outT[((size_t)(b * S_ + srow)) * D_ + h * DH_ + t] =
            (part[0][t] + part[1][t] + part[2][t] + part[3][t]) * inv;
    }
}

// ---------------- gather x rows at global indices ----------------
__global__ __launch_bounds__(256) void k_gather_xg(
    const float* __restrict__ x, const int* __restrict__ idxg, float* __restrict__ xg) {
    int bg = blockIdx.x;
    int b = bg / G_;
    int srow = idxg[bg];
    for (int d = threadIdx.x; d < D_; d += 256)
        xg[(size_t)bg * D_ + d] = x[((size_t)(b * S_ + srow)) * D_ + d];
}

// ---------------- classifier on core rows ----------------
__global__ __launch_bounds__(256) void k_classifier(
    const float* __restrict__ x, const float* __restrict__ Wc,
    const float* __restrict__ bc, const int* __restrict__ lo_p,
    int rows_pb, float* __restrict__ out) {
    int r = blockIdx.x;
    int b = r / rows_pb, i = r % rows_pb;
    int s = lo_p[0] + i;
    int t = threadIdx.x;
    __shared__ float xr[D_];
    __shared__ float red[256];
    const float* xrow = x + ((size_t)(b * S_ + s)) * D_;
    for (int d = t; d < D_; d += 256) xr[d] = xrow[d];
    __syncthreads();
    for (int c = 0; c < C_; c++) {
        float loc = 0.f;
        for (int d = t; d < D_; d += 256) loc += xr[d] * Wc[d * C_ + c];
        red[t] = loc; __syncthreads();
        for (int o = 128; o; o >>= 1) { if (t < o) red[t] += red[t + o]; __syncthreads(); }
        if (t == 0) out[r * C_ + c] = red[0] + bc[c];
        __syncthreads();
    }
}

extern "C" void kernel_launch(void* const* d_in, const int* in_sizes, int n_in,
                              void* d_out, int out_size, void* d_ws, size_t ws_size,
                              hipStream_t stream) {
    (void)in_sizes; (void)n_in; (void)ws_size;
    const float* emb_tok = (const float*)d_in[0];
    const float* emb_pos = (const float*)d_in[1];
    const float* ln_e_s = (const float*)d_in[2];
    const float* ln_e_b = (const float*)d_in[3];
    const float* Wq  = (const float*)d_in[4];
    const float* bq  = (const float*)d_in[5];
    const float* Wk  = (const float*)d_in[6];
    const float* bk  = (const float*)d_in[7];
    const float* Wv  = (const float*)d_in[8];
    const float* bv  = (const float*)d_in[9];
    const float* Wqg = (const float*)d_in[10];
    const float* bqg = (const float*)d_in[11];
    const float* Wkg = (const float*)d_in[12];
    const float* bkg = (const float*)d_in[13];
    const float* Wvg = (const float*)d_in[14];
    const float* bvg = (const float*)d_in[15];
    const float* Wo  = (const float*)d_in[16];
    const float* bo  = (const float*)d_in[17];
    const float* ln1_s = (const float*)d_in[18];
    const float* ln1_b = (const float*)d_in[19];
    const float* Wf1 = (const float*)d_in[20];
    const float* bf1 = (const float*)d_in[21];
    const float* Wf2 = (const float*)d_in[22];
    const float* bf2 = (const float*)d_in[23];
    const float* ln2_s = (const float*)d_in[24];
    const float* ln2_b = (const float*)d_in[25];
    const float* Wc  = (const float*)d_in[26];
    const float* bc  = (const float*)d_in[27];
    const int* input_ids = (const int*)d_in[28];
    const int* attn_mask = (const int*)d_in[29];
    const int* lo        = (const int*)d_in[30];

    const size_t SZ = (size_t)B_ * S_ * D_;   // 6291456 elements
    uint8_t* w = (uint8_t*)d_ws;
    float* x = (float*)w;                               // fp32, 4*SZ bytes
    float* P = (float*)(w + 4 * SZ);                    // fp32, 4*SZ bytes
    uint8_t* big = w + 8 * SZ;                          // 16*SZ bytes region
    unsigned short* qb   = (unsigned short*)(big);            // bf16, 2*SZ
    unsigned short* kb   = (unsigned short*)(big + 2 * SZ);
    unsigned short* vb   = (unsigned short*)(big + 4 * SZ);
    unsigned short* kgab = (unsigned short*)(big + 6 * SZ);
    unsigned short* vgab = (unsigned short*)(big + 8 * SZ);
    float*          T    = (float*)(big + 10 * SZ);           // fp32, 4*SZ
    float*          Hbuf = (float*)big;                       // fp32, 16*SZ (FFN hidden, overlays all of big)
    float* xg = (float*)(w + 24 * SZ);                        // B*G*D fp32
    unsigned short* qgb = (unsigned short*)(w + 24 * SZ + (size_t)B_ * G_ * D_ * 4);
    int* idxg = (int*)(w + 24 * SZ + (size_t)B_ * G_ * D_ * 4 + (size_t)B_ * G_ * D_ * 2);

    const int BS = B_ * S_;

    k_embed_ln<<<BS, 256, 0, stream>>>(input_ids, emb_tok, emb_pos, ln_e_s, ln_e_b, x);
    k_idx<<<1, 64, 0, stream>>>(input_ids, idxg);

    dim3 g_qkv(D_ / 64, BS / 64);      // (12,128)
    dim3 g_f1(FF_ / 64, BS / 64);      // (48,128)
    dim3 g_f2(D_ / 64, BS / 64);
    dim3 g_qg(D_ / 64, (B_ * G_) / 64);// (12,2)

    for (int l = 0; l < L_; l++) {
        const float* Wq_l  = Wq  + (size_t)l * D_ * D_;
        const float* Wk_l  = Wk  + (size_t)l * D_ * D_;
        const float* Wv_l  = Wv  + (size_t)l * D_ * D_;
        const float* Wqg_l = Wqg + (size_t)l * D_ * D_;
        const float* Wkg_l = Wkg + (size_t)l * D_ * D_;
        const float* Wvg_l = Wvg + (size_t)l * D_ * D_;
        const float* Wo_l  = Wo  + (size_t)l * D_ * D_;
        const float* Wf1_l = Wf1 + (size_t)l * D_ * FF_;
        const float* Wf2_l = Wf2 + (size_t)l * FF_ * D_;

        k_gemm<<<g_qkv, 256, 0, stream>>>(x, Wq_l, bq + l * D_, nullptr, qb, BS, D_, D_, 0);
        k_gemm<<<g_qkv, 256, 0, stream>>>(x, Wk_l, bk + l * D_, nullptr, kb, BS, D_, D_, 0);
        k_gemm<<<g_qkv, 256, 0, stream>>>(x, Wv_l, bv + l * D_, nullptr, vb, BS, D_, D_, 0);
        k_local_attn<<<dim3(S_, H_, B_), 256, 0, stream>>>(qb, kb, vb, input_ids, attn_mask, idxg, T);
        k_gemm<<<g_qkv, 256, 0, stream>>>(x, Wkg_l, bkg + l * D_, nullptr, kgab, BS, D_, D_, 0);
        k_gemm<<<g_qkv, 256, 0, stream>>>(x, Wvg_l, bvg + l * D_, nullptr, vgab, BS, D_, D_, 0);
        k_gather_xg<<<B_ * G_, 256, 0, stream>>>(x, idxg, xg);
        k_gemm<<<g_qg, 256, 0, stream>>>(xg, Wqg_l, bqg + l * D_, nullptr, qgb, B_ * G_, D_, D_, 0);
        k_glob_attn<<<dim3(G_, H_, B_), 256, 0, stream>>>(qgb, kgab, vgab, attn_mask, idxg, T);
        k_gemm<<<g_qkv, 256, 0, stream>>>(T, Wo_l, bo + l * D_, P, nullptr, BS, D_, D_, 0);
        k_add_ln<<<BS, 256, 0, stream>>>(x, P, ln1_s + l * D_, ln1_b + l * D_);
        k_gemm<<<g_f1, 256, 0, stream>>>(x, Wf1_l, bf1 + l * FF_, Hbuf, nullptr, BS, FF_, D_, 1);
        k_gemm<<<g_f2, 256, 0, stream>>>(Hbuf, Wf2_l, bf2 + l * D_, P, nullptr, BS, D_, FF_, 0);
        k_add_ln<<<BS, 256, 0, stream>>>(x, P, ln2_s + l * D_, ln2_b + l * D_);
    }

    int rows = out_size / C_;          // 118
    int rows_pb = rows / B_;           // 59
    k_classifier<<<rows, 256, 0, stream>>>(x, Wc, bc, lo, rows_pb, (float*)d_out);
}

// Round 3
// 2982.907 us; speedup vs baseline: 4.3330x; 4.3330x over previous
//
#include <hip/hip_runtime.h>
#include <hip/hip_bf16.h>
#include <stdint.h>

#define B_ 2
#define S_ 4096
#define D_ 768
#define H_ 12
#define DH_ 64
#define L_ 2
#define W_ 256
#define G_ 64
#define FF_ 3072
#define C_ 7
#define SEP_ 2
#define NEG_ (-1000000000.0f)

typedef __attribute__((ext_vector_type(8))) short short8;   // 8 bf16 (4 VGPRs)
typedef __attribute__((ext_vector_type(4))) float f32x4;    // 4 fp32 acc

__device__ __forceinline__ float bfu2f(unsigned short u) {
    return __uint_as_float(((unsigned int)u) << 16);
}
__device__ __forceinline__ float bflo(unsigned int u) { return __uint_as_float(u << 16); }
__device__ __forceinline__ float bfhi(unsigned int u) { return __uint_as_float(u & 0xffff0000u); }
__device__ __forceinline__ unsigned short f2bfu(float f) {
    unsigned int x = __float_as_uint(f);
    unsigned int r = (x + 0x7fffu + ((x >> 16) & 1u)) >> 16;
    return (unsigned short)r;
}
__device__ __forceinline__ float gelu_tanh(float v) {
    float c = 0.7978845608028654f * (v + 0.044715f * v * v * v);
    return 0.5f * v * (1.0f + tanhf(c));
}
__device__ __forceinline__ float dot64q(const float* __restrict__ qv,
                                        const unsigned short* __restrict__ kr) {
    const uint4* k4 = (const uint4*)kr;
    float acc = 0.f;
#pragma unroll
    for (int i = 0; i < 8; i++) {
        uint4 u = k4[i];
        acc += qv[i * 8 + 0] * bflo(u.x); acc += qv[i * 8 + 1] * bfhi(u.x);
        acc += qv[i * 8 + 2] * bflo(u.y); acc += qv[i * 8 + 3] * bfhi(u.y);
        acc += qv[i * 8 + 4] * bflo(u.z); acc += qv[i * 8 + 5] * bfhi(u.z);
        acc += qv[i * 8 + 6] * bflo(u.w); acc += qv[i * 8 + 7] * bfhi(u.w);
    }
    return acc;
}

// ---------------- embedding + LN (writes fp32 x and bf16 xb) ----------------
__global__ __launch_bounds__(256) void k_embed_ln(
    const int* __restrict__ ids, const float* __restrict__ etok,
    const float* __restrict__ epos, const float* __restrict__ lns,
    const float* __restrict__ lnb, float* __restrict__ x,
    unsigned short* __restrict__ xb) {
    int row = blockIdx.x;
    int s = row & (S_ - 1);
    int t = threadIdx.x;
    __shared__ float xr[D_];
    __shared__ float red[256];
    int id = ids[row];
    float loc = 0.f;
    for (int d = t; d < D_; d += 256) {
        float v = etok[(size_t)id * D_ + d] + epos[(size_t)s * D_ + d];
        xr[d] = v; loc += v;
    }
    red[t] = loc; __syncthreads();
    for (int o = 128; o; o >>= 1) { if (t < o) red[t] += red[t + o]; __syncthreads(); }
    float mean = red[0] * (1.0f / D_);
    __syncthreads();
    loc = 0.f;
    for (int d = t; d < D_; d += 256) { float dd = xr[d] - mean; loc += dd * dd; }
    red[t] = loc; __syncthreads();
    for (int o = 128; o; o >>= 1) { if (t < o) red[t] += red[t + o]; __syncthreads(); }
    float rs = rsqrtf(red[0] * (1.0f / D_) + 1e-5f);
    for (int d = t; d < D_; d += 256) {
        float v = (xr[d] - mean) * rs * lns[d] + lnb[d];
        x[(size_t)row * D_ + d] = v;
        xb[(size_t)row * D_ + d] = f2bfu(v);
    }
}

// ---------------- residual add + LN (in-place on x, also writes xb) ----------------
__global__ __launch_bounds__(256) void k_add_ln(
    float* __restrict__ x, const float* __restrict__ y,
    const float* __restrict__ lns, const float* __restrict__ lnb,
    unsigned short* __restrict__ xb) {
    int row = blockIdx.x;
    int t = threadIdx.x;
    __shared__ float xr[D_];
    __shared__ float red[256];
    float loc = 0.f;
    for (int d = t; d < D_; d += 256) {
        float v = x[(size_t)row * D_ + d] + y[(size_t)row * D_ + d];
        xr[d] = v; loc += v;
    }
    red[t] = loc; __syncthreads();
    for (int o = 128; o; o >>= 1) { if (t < o) red[t] += red[t + o]; __syncthreads(); }
    float mean = red[0] * (1.0f / D_);
    __syncthreads();
    loc = 0.f;
    for (int d = t; d < D_; d += 256) { float dd = xr[d] - mean; loc += dd * dd; }
    red[t] = loc; __syncthreads();
    for (int o = 128; o; o >>= 1) { if (t < o) red[t] += red[t + o]; __syncthreads(); }
    float rs = rsqrtf(red[0] * (1.0f / D_) + 1e-5f);
    for (int d = t; d < D_; d += 256) {
        float v = (xr[d] - mean) * rs * lns[d] + lnb[d];
        x[(size_t)row * D_ + d] = v;
        xb[(size_t)row * D_ + d] = f2bfu(v);
    }
}

// ---------------- global-token index extraction ----------------
__global__ void k_idx(const int* __restrict__ ids, int* __restrict__ idxg) {
    int b = threadIdx.x;
    if (b >= B_) return;
    int cnt = 0;
    for (int s = 0; s < S_; s++) {
        if (ids[b * S_ + s] == SEP_ || s == 0) {
            if (cnt < G_) idxg[b * G_ + cnt] = s;
            cnt++;
        }
    }
    for (; cnt < G_; cnt++) idxg[b * G_ + cnt] = 0;
}

// ---------------- MFMA GEMM: C[M,N] = A[M,K](bf16) @ Bw[K,N](fp32->bf16) + bias ----------------
// 128x128 tile, BK=32, 256 threads = 4 waves, each wave 64x64 (4x4 frags of 16x16x32).
__global__ __launch_bounds__(256) void k_gemm_mfma(
    const unsigned short* __restrict__ A, const float* __restrict__ Bw,
    const float* __restrict__ bias, float* __restrict__ Cf,
    unsigned short* __restrict__ Cb, int M, int N, int K, int act) {
    __shared__ unsigned short As[128][40];
    __shared__ unsigned short Bs[128][40];   // transposed: Bs[n][k]
    int t = threadIdx.x;
    int wave = t >> 6, lane = t & 63, l16 = lane & 15, quad = lane >> 4;
    int m0 = blockIdx.y << 7, n0 = blockIdx.x << 7;
    int wm = (wave >> 1) << 6, wn = (wave & 1) << 6;
    f32x4 acc[4][4];
#pragma unroll
    for (int i = 0; i < 4; i++)
#pragma unroll
        for (int j = 0; j < 4; j++) acc[i][j] = (f32x4){0.f, 0.f, 0.f, 0.f};

    int ar = t >> 1, akc = (t & 1) << 4;    // A staging: row, k-chunk(16)
    int bn = t & 127, bkh = (t >> 7) << 4;  // B staging: col n, k-half(16)

    for (int k0 = 0; k0 < K; k0 += 32) {
        const unsigned short* ap = A + (size_t)(m0 + ar) * K + k0 + akc;
        uint4 a0 = *(const uint4*)ap;
        uint4 a1 = *(const uint4*)(ap + 8);
        *(uint4*)&As[ar][akc] = a0;
        *(uint4*)&As[ar][akc + 8] = a1;
        const float* bp = Bw + (size_t)(k0 + bkh) * N + n0 + bn;
        unsigned int pk[8];
#pragma unroll
        for (int i = 0; i < 8; i++) {
            unsigned int lo = f2bfu(bp[(size_t)(2 * i) * N]);
            unsigned int hi = f2bfu(bp[(size_t)(2 * i + 1) * N]);
            pk[i] = lo | (hi << 16);
        }
        *(uint4*)&Bs[bn][bkh] = *(uint4*)&pk[0];
        *(uint4*)&Bs[bn][bkh + 8] = *(uint4*)&pk[4];
        __syncthreads();
        short8 af[4], bf[4];
#pragma unroll
        for (int i = 0; i < 4; i++) af[i] = *(const short8*)&As[wm + i * 16 + l16][quad * 8];
#pragma unroll
        for (int j = 0; j < 4; j++) bf[j] = *(const short8*)&Bs[wn + j * 16 + l16][quad * 8];
#pragma unroll
        for (int i = 0; i < 4; i++)
#pragma unroll
            for (int j = 0; j < 4; j++)
                acc[i][j] = __builtin_amdgcn_mfma_f32_16x16x32_bf16(af[i], bf[j], acc[i][j], 0, 0, 0);
        __syncthreads();
    }
    float bj[4];
#pragma unroll
    for (int j = 0; j < 4; j++) bj[j] = bias[n0 + wn + j * 16 + l16];
#pragma unroll
    for (int i = 0; i < 4; i++)
#pragma unroll
        for (int j = 0; j < 4; j++) {
            int col = n0 + wn + j * 16 + l16;
#pragma unroll
            for (int r = 0; r < 4; r++) {
                int row = m0 + wm + i * 16 + quad * 4 + r;
                float v = acc[i][j][r] + bj[j];
                if (act) v = gelu_tanh(v);
                if (Cf) Cf[(size_t)row * N + col] = v;
                else    Cb[(size_t)row * N + col] = f2bfu(v);
            }
        }
}

// ---------------- MFMA flash local attention: block = (64 queries, h, b) ----------------
__global__ __launch_bounds__(256) void k_lattn(
    const unsigned short* __restrict__ q, const unsigned short* __restrict__ k,
    const unsigned short* __restrict__ v, const int* __restrict__ ids,
    const int* __restrict__ am, const int* __restrict__ idxg,
    unsigned short* __restrict__ Tb) {
    int s0 = blockIdx.x << 6, h = blockIdx.y, b = blockIdx.z;
    int t = threadIdx.x;
    int wave = t >> 6, lane = t & 63, l16 = lane & 15, quad = lane >> 4;

    __shared__ unsigned short Ks[64][72];
    __shared__ unsigned short Vt[64][72];    // transposed: Vt[dh][key]
    __shared__ unsigned short Ps[64][72];
    __shared__ unsigned char keyok[64];

    // Q A-frags in registers: wave's 16 query rows, m = l16
    int qrow = s0 + wave * 16 + l16;
    const unsigned short* qptr = q + ((size_t)(b * S_ + qrow)) * D_ + h * DH_;
    short8 qa0 = *(const short8*)(qptr + quad * 8);
    short8 qa1 = *(const short8*)(qptr + 32 + quad * 8);

    f32x4 O[4];
#pragma unroll
    for (int nf = 0; nf < 4; nf++) O[nf] = (f32x4){0.f, 0.f, 0.f, 0.f};
    float m_run[4] = {-3.4e38f, -3.4e38f, -3.4e38f, -3.4e38f};
    float l_run[4] = {0.f, 0.f, 0.f, 0.f};

    int kbase = s0 - 256;
    int sr = t >> 2, sc = t & 3;            // staging: row, chunk

    for (int tile = 0; tile < 10; tile++) {
        // ---- stage K tile + V tile (transposed) + validity ----
        int sK, sclamp; bool okf;
        if (tile < 9) {
            sK = kbase + tile * 64 + sr;
            bool inr = (sK >= 0) && (sK < S_);
            sclamp = inr ? sK : 0;
            okf = inr && (am[b * S_ + sclamp] != 0) &&
                  !((ids[b * S_ + sclamp] == SEP_) || (sK == 0));
        } else {
            sK = idxg[b * G_ + sr];
            sclamp = sK; okf = true;
        }
        if (sc == 0) keyok[sr] = okf ? 1 : 0;
        const unsigned short* srcK = k + ((size_t)(b * S_ + sclamp)) * D_ + h * DH_;
        const unsigned short* srcV = v + ((size_t)(b * S_ + sclamp)) * D_ + h * DH_;
        uint4 k0v = *(const uint4*)(srcK + sc * 8);
        uint4 k1v = *(const uint4*)(srcK + (sc + 4) * 8);
        uint4 v0v = *(const uint4*)(srcV + sc * 8);
        uint4 v1v = *(const uint4*)(srcV + (sc + 4) * 8);
        *(uint4*)&Ks[sr][sc * 8] = k0v;
        *(uint4*)&Ks[sr][(sc + 4) * 8] = k1v;
        const unsigned int* vw0 = (const unsigned int*)&v0v;
        const unsigned int* vw1 = (const unsigned int*)&v1v;
#pragma unroll
        for (int i = 0; i < 4; i++) {
            Vt[sc * 8 + 2 * i][sr]      = (unsigned short)(vw0[i] & 0xffff);
            Vt[sc * 8 + 2 * i + 1][sr]  = (unsigned short)(vw0[i] >> 16);
            Vt[(sc + 4) * 8 + 2 * i][sr]     = (unsigned short)(vw1[i] & 0xffff);
            Vt[(sc + 4) * 8 + 2 * i + 1][sr] = (unsigned short)(vw1[i] >> 16);
        }
        __syncthreads();

        // ---- S = Q K^T for this tile ----
        f32x4 Sf[4];
#pragma unroll
        for (int nf = 0; nf < 4; nf++) {
            short8 b0 = *(const short8*)&Ks[nf * 16 + l16][quad * 8];
            short8 b1 = *(const short8*)&Ks[nf * 16 + l16][32 + quad * 8];
            f32x4 a = (f32x4){0.f, 0.f, 0.f, 0.f};
            a = __builtin_amdgcn_mfma_f32_16x16x32_bf16(qa0, b0, a, 0, 0, 0);
            a = __builtin_amdgcn_mfma_f32_16x16x32_bf16(qa1, b1, a, 0, 0, 0);
            Sf[nf] = a;
        }
        // ---- mask + online softmax ----
        int ktb = kbase + tile * 64;
        bool kval[4];
#pragma unroll
        for (int nf = 0; nf < 4; nf++) kval[nf] = (tile == 9) || (keyok[nf * 16 + l16] != 0);
        float P_[4][4];
        float mt[4];
#pragma unroll
        for (int r = 0; r < 4; r++) {
            int qs = s0 + wave * 16 + quad * 4 + r;
            float mx = -3.4e38f;
#pragma unroll
            for (int nf = 0; nf < 4; nf++) {
                int ks2 = ktb + nf * 16 + l16;
                bool ok = kval[nf] && ((tile == 9) || (ks2 >= qs - 256 && ks2 <= qs + 256));
                float sv = ok ? Sf[nf][r] * 0.125f : NEG_;
                P_[nf][r] = sv;
                mx = fmaxf(mx, sv);
            }
            mt[r] = mx;
        }
#pragma unroll
        for (int off = 1; off < 16; off <<= 1)
#pragma unroll
            for (int r = 0; r < 4; r++) mt[r] = fmaxf(mt[r], __shfl_xor(mt[r], off));
        float alpha[4], lt[4];
#pragma unroll
        for (int r = 0; r < 4; r++) {
            float mn = fmaxf(m_run[r], mt[r]);
            alpha[r] = __expf(m_run[r] - mn);
            m_run[r] = mn; lt[r] = 0.f;
        }
#pragma unroll
        for (int nf = 0; nf < 4; nf++)
#pragma unroll
            for (int r = 0; r < 4; r++) {
                float p = (P_[nf][r] > -1.0e8f) ? __expf(P_[nf][r] - m_run[r]) : 0.f;
                P_[nf][r] = p; lt[r] += p;
            }
#pragma unroll
        for (int off = 1; off < 16; off <<= 1)
#pragma unroll
            for (int r = 0; r < 4; r++) lt[r] += __shfl_xor(lt[r], off);
#pragma unroll
        for (int r = 0; r < 4; r++) l_run[r] = l_run[r] * alpha[r] + lt[r];
#pragma unroll
        for (int nf = 0; nf < 4; nf++) {
            O[nf][0] *= alpha[0]; O[nf][1] *= alpha[1];
            O[nf][2] *= alpha[2]; O[nf][3] *= alpha[3];
        }
        // ---- P through LDS (C-layout -> A-layout), per-wave private rows ----
#pragma unroll
        for (int nf = 0; nf < 4; nf++)
#pragma unroll
            for (int r = 0; r < 4; r++)
                Ps[wave * 16 + quad * 4 + r][nf * 16 + l16] = f2bfu(P_[nf][r]);
        // ---- O += P V ----
#pragma unroll
        for (int hh = 0; hh < 2; hh++) {
            short8 pa = *(const short8*)&Ps[wave * 16 + l16][hh * 32 + quad * 8];
#pragma unroll
            for (int nf = 0; nf < 4; nf++) {
                short8 vb8 = *(const short8*)&Vt[nf * 16 + l16][hh * 32 + quad * 8];
                O[nf] = __builtin_amdgcn_mfma_f32_16x16x32_bf16(pa, vb8, O[nf], 0, 0, 0);
            }
        }
        __syncthreads();
    }
    // ---- epilogue ----
#pragma unroll
    for (int r = 0; r < 4; r++) {
        int qs = s0 + wave * 16 + quad * 4 + r;
        float invl = 1.0f / l_run[r];
        size_t base = ((size_t)(b * S_ + qs)) * D_ + h * DH_;
#pragma unroll
        for (int nf = 0; nf < 4; nf++)
            Tb[base + nf * 16 + l16] = f2bfu(O[nf][r] * invl);
    }
}

// ---------------- VALU GEMM (small M): C = A(f32) @ B(f32) + bias ----------------
__global__ __launch_bounds__(256) void k_gemm(
    const float* __restrict__ A, const float* __restrict__ Bw,
    const float* __restrict__ bias, float* __restrict__ Cf,
    unsigned short* __restrict__ Cb, int M, int N, int K, int act) {
    __shared__ float As[16][68];
    __shared__ float Bs[16][68];
    int tl = threadIdx.x;
    int tx = tl & 15, ty = tl >> 4;
    int m0 = blockIdx.y << 6, n0 = blockIdx.x << 6;
    float c[4][4] = {{0.f}};
    int arow = tl >> 2, akk = (tl & 3) << 2;
    int bkk = tl >> 4, bcol = (tl & 15) << 2;
    for (int k0 = 0; k0 < K; k0 += 16) {
        float4 a4 = *(const float4*)(A + (size_t)(m0 + arow) * K + k0 + akk);
        As[akk + 0][arow] = a4.x; As[akk + 1][arow] = a4.y;
        As[akk + 2][arow] = a4.z; As[akk + 3][arow] = a4.w;
        float4 b4 = *(const float4*)(Bw + (size_t)(k0 + bkk) * N + n0 + bcol);
        Bs[bkk][bcol + 0] = b4.x; Bs[bkk][bcol + 1] = b4.y;
        Bs[bkk][bcol + 2] = b4.z; Bs[bkk][bcol + 3] = b4.w;
        __syncthreads();
#pragma unroll
        for (int kk = 0; kk < 16; kk++) {
            float4 av = *(const float4*)&As[kk][ty << 2];
            float4 bv = *(const float4*)&Bs[kk][tx << 2];
            float aa[4] = {av.x, av.y, av.z, av.w};
            float bb[4] = {bv.x, bv.y, bv.z, bv.w};
#pragma unroll
            for (int i = 0; i < 4; i++)
#pragma unroll
                for (int j = 0; j < 4; j++) c[i][j] += aa[i] * bb[j];
        }
        __syncthreads();
    }
    float bias4[4];
#pragma unroll
    for (int j = 0; j < 4; j++) bias4[j] = bias[n0 + (tx << 2) + j];
#pragma unroll
    for (int i = 0; i < 4; i++) {
        int mrow = m0 + (ty << 2) + i;
        float v0 = c[i][0] + bias4[0], v1 = c[i][1] + bias4[1];
        float v2 = c[i][2] + bias4[2], v3 = c[i][3] + bias4[3];
        if (act) { v0 = gelu_tanh(v0); v1 = gelu_tanh(v1); v2 = gelu_tanh(v2); v3 = gelu_tanh(v3); }
        if (Cf) {
            float4 o; o.x = v0; o.y = v1; o.z = v2; o.w = v3;
            *(float4*)(Cf + (size_t)mrow * N + n0 + (tx << 2)) = o;
        } else {
            ushort4 o; o.x = f2bfu(v0); o.y = f2bfu(v1); o.z = f2bfu(v2); o.w = f2bfu(v3);
            *(ushort4*)(Cb + (size_t)mrow * N + n0 + (tx << 2)) = o;
        }
    }
}

// ---------------- global-query full attention (writes bf16 Tb rows) ----------------
__global__ __launch_bounds__(256) void k_glob_attn(
    const unsigned short* __restrict__ qg, const unsigned short* __restrict__ kga,
    const unsigned short* __restrict__ vga, const int* __restrict__ am,
    const int* __restrict__ idxg, unsigned short* __restrict__ Tb) {
    int g = blockIdx.x, h = blockIdx.y, b = blockIdx.z;
    int t = threadIdx.x;
    __shared__ float qv[DH_];
    __shared__ float sc[S_];
    __shared__ float red[256];
    __shared__ float part[4][DH_];
    if (t < DH_) qv[t] = bfu2f(qg[((size_t)(b * G_ + g)) * D_ + h * DH_ + t]);
    __syncthreads();
    for (int j = t; j < S_; j += 256) {
        float sv = NEG_;
        if (am[b * S_ + j] != 0)
            sv = dot64q(qv, kga + ((size_t)(b * S_ + j)) * D_ + h * DH_) * 0.125f;
        sc[j] = sv;
    }
    __syncthreads();
    float lm = -3.4e38f;
    for (int j = t; j < S_; j += 256) lm = fmaxf(lm, sc[j]);
    red[t] = lm; __syncthreads();
    for (int o = 128; o; o >>= 1) { if (t < o) red[t] = fmaxf(red[t], red[t + o]); __syncthreads(); }
    float mx = red[0];
    __syncthreads();
    float ls = 0.f;
    for (int j = t; j < S_; j += 256) { float e = __expf(sc[j] - mx); sc[j] = e; ls += e; }
    red[t] = ls; __syncthreads();
    for (int o = 128; o; o >>= 1) { if (t < o) red[t] += red[t + o]; __syncthreads(); }
    float inv = 1.0f / red[0];
    __syncthreads();
    int d = t & 63, cch = t >> 6;
    float acc = 0.f;
    for (int j = cch; j < S_; j += 4)
        acc += sc[j] * bfu2f(vga[((size_t)(b * S_ + j)) * D_ + h * DH_ + d]);
    part[cch][d] = acc;
    __syncthreads();
    if (t < DH_) {
        int srow = idxg[b * G_ + g];
        Tb[((size_t)(b * S_ + srow)) * D_ + h * DH_ + t] =
            f2bfu((part[0][t] + part[1][t] + part[2][t] + part[3][t]) * inv);
    }
}

// ---------------- gather x rows at global indices ----------------
__global__ __launch_bounds__(256) void k_gather_xg(
    const float* __restrict__ x, const int* __restrict__ idxg, float* __restrict__ xg) {
    int bg = blockIdx.x;
    int b = bg / G_;
    int srow = idxg[bg];
    for (int d = threadIdx.x; d < D_; d += 256)
        xg[(size_t)bg * D_ + d] = x[((size_t)(b * S_ + srow)) * D_ + d];
}

// ---------------- classifier on core rows ----------------
__global__ __launch_bounds__(256) void k_classifier(
    const float* __restrict__ x, const float* __restrict__ Wc,
    const float* __restrict__ bc, const int* __restrict__ lo_p,
    int rows_pb, float* __restrict__ out) {
    int r = blockIdx.x;
    int b = r / rows_pb, i = r % rows_pb;
    int s = lo_p[0] + i;
    int t = threadIdx.x;
    __shared__ float xr[D_];
    __shared__ float red[256];
    const float* xrow = x + ((size_t)(b * S_ + s)) * D_;
    for (int d = t; d < D_; d += 256) xr[d] = xrow[d];
    __syncthreads();
    for (int c = 0; c < C_; c++) {
        float loc = 0.f;
        for (int d = t; d < D_; d += 256) loc += xr[d] * Wc[d * C_ + c];
        red[t] = loc; __syncthreads();
        for (int o = 128; o; o >>= 1) { if (t < o) red[t] += red[t + o]; __syncthreads(); }
        if (t == 0) out[r * C_ + c] = red[0] + bc[c];
        __syncthreads();
    }
}

extern "C" void kernel_launch(void* const* d_in, const int* in_sizes, int n_in,
                              void* d_out, int out_size, void* d_ws, size_t ws_size,
                              hipStream_t stream) {
    (void)in_sizes; (void)n_in; (void)ws_size;
    const float* emb_tok = (const float*)d_in[0];
    const float* emb_pos = (const float*)d_in[1];
    const float* ln_e_s = (const float*)d_in[2];
    const float* ln_e_b = (const float*)d_in[3];
    const float* Wq  = (const float*)d_in[4];
    const float* bq  = (const float*)d_in[5];
    const float* Wk  = (const float*)d_in[6];
    const float* bk  = (const float*)d_in[7];
    const float* Wv  = (const float*)d_in[8];
    const float* bv  = (const float*)d_in[9];
    const float* Wqg = (const float*)d_in[10];
    const float* bqg = (const float*)d_in[11];
    const float* Wkg = (const float*)d_in[12];
    const float* bkg = (const float*)d_in[13];
    const float* Wvg = (const float*)d_in[14];
    const float* bvg = (const float*)d_in[15];
    const float* Wo  = (const float*)d_in[16];
    const float* bo  = (const float*)d_in[17];
    const float* ln1_s = (const float*)d_in[18];
    const float* ln1_b = (const float*)d_in[19];
    const float* Wf1 = (const float*)d_in[20];
    const float* bf1 = (const float*)d_in[21];
    const float* Wf2 = (const float*)d_in[22];
    const float* bf2 = (const float*)d_in[23];
    const float* ln2_s = (const float*)d_in[24];
    const float* ln2_b = (const float*)d_in[25];
    const float* Wc  = (const float*)d_in[26];
    const float* bc  = (const float*)d_in[27];
    const int* input_ids = (const int*)d_in[28];
    const int* attn_mask = (const int*)d_in[29];
    const int* lo        = (const int*)d_in[30];

    const size_t SZB = (size_t)B_ * S_ * D_;   // 6291456 (elements; also byte unit)
    uint8_t* w = (uint8_t*)d_ws;
    float*          x    = (float*)w;                        // fp32  [0,4)
    unsigned short* xb   = (unsigned short*)(w + 4 * SZB);   // bf16  [4,6)
    float*          P    = (float*)(w + 6 * SZB);            // fp32  [6,10)
    unsigned short* qb   = (unsigned short*)(w + 10 * SZB);  // bf16  [10,12)
    unsigned short* kb   = (unsigned short*)(w + 12 * SZB);
    unsigned short* vb   = (unsigned short*)(w + 14 * SZB);
    unsigned short* kgab = (unsigned short*)(w + 16 * SZB);
    unsigned short* vgab = (unsigned short*)(w + 18 * SZB);
    unsigned short* Hb   = (unsigned short*)(w + 10 * SZB);  // bf16 hidden, overlays qb..kgab (dead by FFN)
    unsigned short* Tb   = (unsigned short*)(w + 20 * SZB);  // bf16  [20,22)
    float* xg = (float*)(w + 22 * SZB);
    unsigned short* qgb = (unsigned short*)(w + 22 * SZB + (size_t)B_ * G_ * D_ * 4);
    int* idxg = (int*)(w + 22 * SZB + (size_t)B_ * G_ * D_ * 4 + (size_t)B_ * G_ * D_ * 2);

    const int BS = B_ * S_;

    k_embed_ln<<<BS, 256, 0, stream>>>(input_ids, emb_tok, emb_pos, ln_e_s, ln_e_b, x, xb);
    k_idx<<<1, 64, 0, stream>>>(input_ids, idxg);

    dim3 g_d(D_ / 128, BS / 128);       // (6, 64)
    dim3 g_ff(FF_ / 128, BS / 128);     // (24, 64)
    dim3 g_qg(D_ / 64, (B_ * G_) / 64); // (12, 2) small VALU path

    for (int l = 0; l < L_; l++) {
        const float* Wq_l  = Wq  + (size_t)l * D_ * D_;
        const float* Wk_l  = Wk  + (size_t)l * D_ * D_;
        const float* Wv_l  = Wv  + (size_t)l * D_ * D_;
        const float* Wqg_l = Wqg + (size_t)l * D_ * D_;
        const float* Wkg_l = Wkg + (size_t)l * D_ * D_;
        const float* Wvg_l = Wvg + (size_t)l * D_ * D_;
        const float* Wo_l  = Wo  + (size_t)l * D_ * D_;
        const float* Wf1_l = Wf1 + (size_t)l * D_ * FF_;
        const float* Wf2_l = Wf2 + (size_t)l * FF_ * D_;

        k_gemm_mfma<<<g_d, 256, 0, stream>>>(xb, Wq_l, bq + l * D_, nullptr, qb, BS, D_, D_, 0);
        k_gemm_mfma<<<g_d, 256, 0, stream>>>(xb, Wk_l, bk + l * D_, nullptr, kb, BS, D_, D_, 0);
        k_gemm_mfma<<<g_d, 256, 0, stream>>>(xb, Wv_l, bv + l * D_, nullptr, vb, BS, D_, D_, 0);
        k_gemm_mfma<<<g_d, 256, 0, stream>>>(xb, Wkg_l, bkg + l * D_, nullptr, kgab, BS, D_, D_, 0);
        k_gemm_mfma<<<g_d, 256, 0, stream>>>(xb, Wvg_l, bvg + l * D_, nullptr, vgab, BS, D_, D_, 0);
        k_lattn<<<dim3(S_ / 64, H_, B_), 256, 0, stream>>>(qb, kb, vb, input_ids, attn_mask, idxg, Tb);
        k_gather_xg<<<B_ * G_, 256, 0, stream>>>(x, idxg, xg);
        k_gemm<<<g_qg, 256, 0, stream>>>(xg, Wqg_l, bqg + l * D_, nullptr, qgb, B_ * G_, D_, D_, 0);
        k_glob_attn<<<dim3(G_, H_, B_), 256, 0, stream>>>(qgb, kgab, vgab, attn_mask, idxg, Tb);
        k_gemm_mfma<<<g_d, 256, 0, stream>>>(Tb, Wo_l, bo + l * D_, P, nullptr, BS, D_, D_, 0);
        k_add_ln<<<BS, 256, 0, stream>>>(x, P, ln1_s + l * D_, ln1_b + l * D_, xb);
        k_gemm_mfma<<<g_ff, 256, 0, stream>>>(xb, Wf1_l, bf1 + l * FF_, nullptr, Hb, BS, FF_, D_, 1);
        k_gemm_mfma<<<g_d, 256, 0, stream>>>(Hb, Wf2_l, bf2 + l * D_, P, nullptr, BS, D_, FF_, 0);
        k_add_ln<<<BS, 256, 0, stream>>>(x, P, ln2_s + l * D_, ln2_b + l * D_, xb);
    }

    int rows = out_size / C_;
    int rows_pb = rows / B_;
    k_classifier<<<rows, 256, 0, stream>>>(x, Wc, bc, lo, rows_pb, (float*)d_out);
}

// Round 4
// 1881.051 us; speedup vs baseline: 6.8711x; 1.5858x over previous
//
#include <hip/hip_runtime.h>
#include <hip/hip_bf16.h>
#include <stdint.h>

#define B_ 2
#define S_ 4096
#define D_ 768
#define H_ 12
#define DH_ 64
#define L_ 2
#define W_ 256
#define G_ 64
#define FF_ 3072
#define C_ 7
#define SEP_ 2
#define NEG_ (-1000000000.0f)
#define NC_ 16          // key chunks for global attention (4096/256)

typedef __attribute__((ext_vector_type(8))) short short8;   // 8 bf16 (4 VGPRs)
typedef __attribute__((ext_vector_type(4))) float f32x4;    // 4 fp32 acc

__device__ __forceinline__ float bfu2f(unsigned short u) {
    return __uint_as_float(((unsigned int)u) << 16);
}
__device__ __forceinline__ unsigned short f2bfu(float f) {
    unsigned int x = __float_as_uint(f);
    unsigned int r = (x + 0x7fffu + ((x >> 16) & 1u)) >> 16;
    return (unsigned short)r;
}
__device__ __forceinline__ float gelu_tanh(float v) {
    float c = 0.7978845608028654f * (v + 0.044715f * v * v * v);
    return 0.5f * v * (1.0f + tanhf(c));
}

// ---------------- embedding + LN (writes fp32 x and bf16 xb) ----------------
__global__ __launch_bounds__(256) void k_embed_ln(
    const int* __restrict__ ids, const float* __restrict__ etok,
    const float* __restrict__ epos, const float* __restrict__ lns,
    const float* __restrict__ lnb, float* __restrict__ x,
    unsigned short* __restrict__ xb) {
    int row = blockIdx.x;
    int s = row & (S_ - 1);
    int t = threadIdx.x;
    __shared__ float xr[D_];
    __shared__ float red[256];
    int id = ids[row];
    float loc = 0.f;
    for (int d = t; d < D_; d += 256) {
        float v = etok[(size_t)id * D_ + d] + epos[(size_t)s * D_ + d];
        xr[d] = v; loc += v;
    }
    red[t] = loc; __syncthreads();
    for (int o = 128; o; o >>= 1) { if (t < o) red[t] += red[t + o]; __syncthreads(); }
    float mean = red[0] * (1.0f / D_);
    __syncthreads();
    loc = 0.f;
    for (int d = t; d < D_; d += 256) { float dd = xr[d] - mean; loc += dd * dd; }
    red[t] = loc; __syncthreads();
    for (int o = 128; o; o >>= 1) { if (t < o) red[t] += red[t + o]; __syncthreads(); }
    float rs = rsqrtf(red[0] * (1.0f / D_) + 1e-5f);
    for (int d = t; d < D_; d += 256) {
        float v = (xr[d] - mean) * rs * lns[d] + lnb[d];
        x[(size_t)row * D_ + d] = v;
        xb[(size_t)row * D_ + d] = f2bfu(v);
    }
}

// ---------------- residual add + LN (in-place on x, also writes xb) ----------------
__global__ __launch_bounds__(256) void k_add_ln(
    float* __restrict__ x, const float* __restrict__ y,
    const float* __restrict__ lns, const float* __restrict__ lnb,
    unsigned short* __restrict__ xb) {
    int row = blockIdx.x;
    int t = threadIdx.x;
    __shared__ float xr[D_];
    __shared__ float red[256];
    float loc = 0.f;
    for (int d = t; d < D_; d += 256) {
        float v = x[(size_t)row * D_ + d] + y[(size_t)row * D_ + d];
        xr[d] = v; loc += v;
    }
    red[t] = loc; __syncthreads();
    for (int o = 128; o; o >>= 1) { if (t < o) red[t] += red[t + o]; __syncthreads(); }
    float mean = red[0] * (1.0f / D_);
    __syncthreads();
    loc = 0.f;
    for (int d = t; d < D_; d += 256) { float dd = xr[d] - mean; loc += dd * dd; }
    red[t] = loc; __syncthreads();
    for (int o = 128; o; o >>= 1) { if (t < o) red[t] += red[t + o]; __syncthreads(); }
    float rs = rsqrtf(red[0] * (1.0f / D_) + 1e-5f);
    for (int d = t; d < D_; d += 256) {
        float v = (xr[d] - mean) * rs * lns[d] + lnb[d];
        x[(size_t)row * D_ + d] = v;
        xb[(size_t)row * D_ + d] = f2bfu(v);
    }
}

// ---------------- global-token index extraction ----------------
__global__ void k_idx(const int* __restrict__ ids, int* __restrict__ idxg) {
    int b = threadIdx.x;
    if (b >= B_) return;
    int cnt = 0;
    for (int s = 0; s < S_; s++) {
        if (ids[b * S_ + s] == SEP_ || s == 0) {
            if (cnt < G_) idxg[b * G_ + cnt] = s;
            cnt++;
        }
    }
    for (; cnt < G_; cnt++) idxg[b * G_ + cnt] = 0;
}

// ---------------- MFMA GEMM: C[M,N] = A[M,K](bf16) @ Bw[K,N](fp32->bf16) + bias ----------------
// 128x128 tile, BK=32, 4 waves, each wave 64x64. hm=1: bf16 out in head-major [B,H,S,DH].
__global__ __launch_bounds__(256) void k_gemm_mfma(
    const unsigned short* __restrict__ A, const float* __restrict__ Bw,
    const float* __restrict__ bias, float* __restrict__ Cf,
    unsigned short* __restrict__ Cb, int M, int N, int K, int act, int hm) {
    __shared__ unsigned short As[128][40];
    __shared__ unsigned short Bs[128][40];   // transposed: Bs[n][k]
    int t = threadIdx.x;
    int wave = t >> 6, lane = t & 63, l16 = lane & 15, quad = lane >> 4;
    int m0 = blockIdx.y << 7, n0 = blockIdx.x << 7;
    int wm = (wave >> 1) << 6, wn = (wave & 1) << 6;
    f32x4 acc[4][4];
#pragma unroll
    for (int i = 0; i < 4; i++)
#pragma unroll
        for (int j = 0; j < 4; j++) acc[i][j] = (f32x4){0.f, 0.f, 0.f, 0.f};

    int ar = t >> 1, akc = (t & 1) << 4;
    int bn = t & 127, bkh = (t >> 7) << 4;

    for (int k0 = 0; k0 < K; k0 += 32) {
        const unsigned short* ap = A + (size_t)(m0 + ar) * K + k0 + akc;
        uint4 a0 = *(const uint4*)ap;
        uint4 a1 = *(const uint4*)(ap + 8);
        *(uint4*)&As[ar][akc] = a0;
        *(uint4*)&As[ar][akc + 8] = a1;
        const float* bp = Bw + (size_t)(k0 + bkh) * N + n0 + bn;
        unsigned int pk[8];
#pragma unroll
        for (int i = 0; i < 8; i++) {
            unsigned int lo = f2bfu(bp[(size_t)(2 * i) * N]);
            unsigned int hi = f2bfu(bp[(size_t)(2 * i + 1) * N]);
            pk[i] = lo | (hi << 16);
        }
        *(uint4*)&Bs[bn][bkh] = *(uint4*)&pk[0];
        *(uint4*)&Bs[bn][bkh + 8] = *(uint4*)&pk[4];
        __syncthreads();
        short8 af[4], bf[4];
#pragma unroll
        for (int i = 0; i < 4; i++) af[i] = *(const short8*)&As[wm + i * 16 + l16][quad * 8];
#pragma unroll
        for (int j = 0; j < 4; j++) bf[j] = *(const short8*)&Bs[wn + j * 16 + l16][quad * 8];
#pragma unroll
        for (int i = 0; i < 4; i++)
#pragma unroll
            for (int j = 0; j < 4; j++)
                acc[i][j] = __builtin_amdgcn_mfma_f32_16x16x32_bf16(af[i], bf[j], acc[i][j], 0, 0, 0);
        __syncthreads();
    }
    float bj[4];
#pragma unroll
    for (int j = 0; j < 4; j++) bj[j] = bias[n0 + wn + j * 16 + l16];
#pragma unroll
    for (int i = 0; i < 4; i++)
#pragma unroll
        for (int j = 0; j < 4; j++) {
            int col = n0 + wn + j * 16 + l16;
#pragma unroll
            for (int r = 0; r < 4; r++) {
                int row = m0 + wm + i * 16 + quad * 4 + r;
                float v = acc[i][j][r] + bj[j];
                if (act) v = gelu_tanh(v);
                if (Cf) {
                    Cf[(size_t)row * N + col] = v;
                } else if (hm) {
                    size_t adr = ((((size_t)(row >> 12)) * H_ + (col >> 6)) * S_ +
                                  (row & (S_ - 1))) * DH_ + (col & 63);
                    Cb[adr] = f2bfu(v);
                } else {
                    Cb[(size_t)row * N + col] = f2bfu(v);
                }
            }
        }
}

// ---------------- MFMA flash local attention: block = (64 queries, h, b) ----------------
// q,k,v head-major [B,H,S,DH]. Output Tb row-major [B*S, D] bf16.
__global__ __launch_bounds__(256) void k_lattn(
    const unsigned short* __restrict__ q, const unsigned short* __restrict__ k,
    const unsigned short* __restrict__ v, const int* __restrict__ ids,
    const int* __restrict__ am, const int* __restrict__ idxg,
    unsigned short* __restrict__ Tb) {
    int s0 = blockIdx.x << 6, h = blockIdx.y, b = blockIdx.z;
    int t = threadIdx.x;
    int wave = t >> 6, lane = t & 63, l16 = lane & 15, quad = lane >> 4;

    __shared__ unsigned short Ks[64][72];
    __shared__ unsigned short Vt[64][72];
    __shared__ unsigned short Ps[64][72];
    __shared__ unsigned char keyok[64];

    const size_t headbase = (((size_t)b * H_) + h) * S_;
    int qrow = s0 + wave * 16 + l16;
    const unsigned short* qptr = q + (headbase + qrow) * DH_;
    short8 qa0 = *(const short8*)(qptr + quad * 8);
    short8 qa1 = *(const short8*)(qptr + 32 + quad * 8);

    f32x4 O[4];
#pragma unroll
    for (int nf = 0; nf < 4; nf++) O[nf] = (f32x4){0.f, 0.f, 0.f, 0.f};
    float m_run[4] = {-3.4e38f, -3.4e38f, -3.4e38f, -3.4e38f};
    float l_run[4] = {0.f, 0.f, 0.f, 0.f};

    int kbase = s0 - 256;
    int sr = t >> 2, sc = t & 3;

    for (int tile = 0; tile < 10; tile++) {
        int sK, sclamp; bool okf;
        if (tile < 9) {
            sK = kbase + tile * 64 + sr;
            bool inr = (sK >= 0) && (sK < S_);
            sclamp = inr ? sK : 0;
            okf = inr && (am[b * S_ + sclamp] != 0) &&
                  !((ids[b * S_ + sclamp] == SEP_) || (sK == 0));
        } else {
            sK = idxg[b * G_ + sr];
            sclamp = sK; okf = true;
        }
        if (sc == 0) keyok[sr] = okf ? 1 : 0;
        const unsigned short* srcK = k + (headbase + sclamp) * DH_;
        const unsigned short* srcV = v + (headbase + sclamp) * DH_;
        uint4 k0v = *(const uint4*)(srcK + sc * 8);
        uint4 k1v = *(const uint4*)(srcK + (sc + 4) * 8);
        uint4 v0v = *(const uint4*)(srcV + sc * 8);
        uint4 v1v = *(const uint4*)(srcV + (sc + 4) * 8);
        *(uint4*)&Ks[sr][sc * 8] = k0v;
        *(uint4*)&Ks[sr][(sc + 4) * 8] = k1v;
        const unsigned int* vw0 = (const unsigned int*)&v0v;
        const unsigned int* vw1 = (const unsigned int*)&v1v;
#pragma unroll
        for (int i = 0; i < 4; i++) {
            Vt[sc * 8 + 2 * i][sr]      = (unsigned short)(vw0[i] & 0xffff);
            Vt[sc * 8 + 2 * i + 1][sr]  = (unsigned short)(vw0[i] >> 16);
            Vt[(sc + 4) * 8 + 2 * i][sr]     = (unsigned short)(vw1[i] & 0xffff);
            Vt[(sc + 4) * 8 + 2 * i + 1][sr] = (unsigned short)(vw1[i] >> 16);
        }
        __syncthreads();

        f32x4 Sf[4];
#pragma unroll
        for (int nf = 0; nf < 4; nf++) {
            short8 b0 = *(const short8*)&Ks[nf * 16 + l16][quad * 8];
            short8 b1 = *(const short8*)&Ks[nf * 16 + l16][32 + quad * 8];
            f32x4 a = (f32x4){0.f, 0.f, 0.f, 0.f};
            a = __builtin_amdgcn_mfma_f32_16x16x32_bf16(qa0, b0, a, 0, 0, 0);
            a = __builtin_amdgcn_mfma_f32_16x16x32_bf16(qa1, b1, a, 0, 0, 0);
            Sf[nf] = a;
        }
        int ktb = kbase + tile * 64;
        bool kval[4];
#pragma unroll
        for (int nf = 0; nf < 4; nf++) kval[nf] = (tile == 9) || (keyok[nf * 16 + l16] != 0);
        float P_[4][4];
        float mt[4];
#pragma unroll
        for (int r = 0; r < 4; r++) {
            int qs = s0 + wave * 16 + quad * 4 + r;
            float mx = -3.4e38f;
#pragma unroll
            for (int nf = 0; nf < 4; nf++) {
                int ks2 = ktb + nf * 16 + l16;
                bool ok = kval[nf] && ((tile == 9) || (ks2 >= qs - 256 && ks2 <= qs + 256));
                float sv = ok ? Sf[nf][r] * 0.125f : NEG_;
                P_[nf][r] = sv;
                mx = fmaxf(mx, sv);
            }
            mt[r] = mx;
        }
#pragma unroll
        for (int off = 1; off < 16; off <<= 1)
#pragma unroll
            for (int r = 0; r < 4; r++) mt[r] = fmaxf(mt[r], __shfl_xor(mt[r], off));
        float alpha[4], lt[4];
#pragma unroll
        for (int r = 0; r < 4; r++) {
            float mn = fmaxf(m_run[r], mt[r]);
            alpha[r] = __expf(m_run[r] - mn);
            m_run[r] = mn; lt[r] = 0.f;
        }
#pragma unroll
        for (int nf = 0; nf < 4; nf++)
#pragma unroll
            for (int r = 0; r < 4; r++) {
                float p = (P_[nf][r] > -1.0e8f) ? __expf(P_[nf][r] - m_run[r]) : 0.f;
                P_[nf][r] = p; lt[r] += p;
            }
#pragma unroll
        for (int off = 1; off < 16; off <<= 1)
#pragma unroll
            for (int r = 0; r < 4; r++) lt[r] += __shfl_xor(lt[r], off);
#pragma unroll
        for (int r = 0; r < 4; r++) l_run[r] = l_run[r] * alpha[r] + lt[r];
#pragma unroll
        for (int nf = 0; nf < 4; nf++) {
            O[nf][0] *= alpha[0]; O[nf][1] *= alpha[1];
            O[nf][2] *= alpha[2]; O[nf][3] *= alpha[3];
        }
#pragma unroll
        for (int nf = 0; nf < 4; nf++)
#pragma unroll
            for (int r = 0; r < 4; r++)
                Ps[wave * 16 + quad * 4 + r][nf * 16 + l16] = f2bfu(P_[nf][r]);
#pragma unroll
        for (int hh = 0; hh < 2; hh++) {
            short8 pa = *(const short8*)&Ps[wave * 16 + l16][hh * 32 + quad * 8];
#pragma unroll
            for (int nf = 0; nf < 4; nf++) {
                short8 vb8 = *(const short8*)&Vt[nf * 16 + l16][hh * 32 + quad * 8];
                O[nf] = __builtin_amdgcn_mfma_f32_16x16x32_bf16(pa, vb8, O[nf], 0, 0, 0);
            }
        }
        __syncthreads();
    }
#pragma unroll
    for (int r = 0; r < 4; r++) {
        int qs = s0 + wave * 16 + quad * 4 + r;
        float invl = 1.0f / l_run[r];
        size_t base = ((size_t)(b * S_ + qs)) * D_ + h * DH_;
#pragma unroll
        for (int nf = 0; nf < 4; nf++)
            Tb[base + nf * 16 + l16] = f2bfu(O[nf][r] * invl);
    }
}

// ---------------- MFMA global-query attention, pass 1: partials per key chunk ----------------
// qg: bf16 [B*G, D] row-major; kga/vga head-major [B,H,S,DH].
// Opart[(b*H+h)*NC+c][g][dh] fp32 (un-normalized), mbuf/lbuf[(b*H+h)*NC+c][g].
__global__ __launch_bounds__(256) void k_gattn_part(
    const unsigned short* __restrict__ qg, const unsigned short* __restrict__ kga,
    const unsigned short* __restrict__ vga, const int* __restrict__ am,
    float* __restrict__ Opart, float* __restrict__ mbuf, float* __restrict__ lbuf) {
    int c = blockIdx.x, h = blockIdx.y, b = blockIdx.z;
    int t = threadIdx.x;
    int wave = t >> 6, lane = t & 63, l16 = lane & 15, quad = lane >> 4;

    __shared__ unsigned short Ks[64][72];
    __shared__ unsigned short Vt[64][72];
    __shared__ unsigned short Ps[64][72];
    __shared__ unsigned char keyok[64];

    const size_t headbase = (((size_t)b * H_) + h) * S_;
    int grow = wave * 16 + l16;
    const unsigned short* qptr = qg + ((size_t)(b * G_ + grow)) * D_ + h * DH_;
    short8 qa0 = *(const short8*)(qptr + quad * 8);
    short8 qa1 = *(const short8*)(qptr + 32 + quad * 8);

    f32x4 O[4];
#pragma unroll
    for (int nf = 0; nf < 4; nf++) O[nf] = (f32x4){0.f, 0.f, 0.f, 0.f};
    float m_run[4] = {-3.4e38f, -3.4e38f, -3.4e38f, -3.4e38f};
    float l_run[4] = {0.f, 0.f, 0.f, 0.f};

    int kbase = c * 256;
    int sr = t >> 2, sc = t & 3;

    for (int tile = 0; tile < 4; tile++) {
        int sK = kbase + tile * 64 + sr;
        if (sc == 0) keyok[sr] = (am[b * S_ + sK] != 0) ? 1 : 0;
        const unsigned short* srcK = kga + (headbase + sK) * DH_;
        const unsigned short* srcV = vga + (headbase + sK) * DH_;
        uint4 k0v = *(const uint4*)(srcK + sc * 8);
        uint4 k1v = *(const uint4*)(srcK + (sc + 4) * 8);
        uint4 v0v = *(const uint4*)(srcV + sc * 8);
        uint4 v1v = *(const uint4*)(srcV + (sc + 4) * 8);
        *(uint4*)&Ks[sr][sc * 8] = k0v;
        *(uint4*)&Ks[sr][(sc + 4) * 8] = k1v;
        const unsigned int* vw0 = (const unsigned int*)&v0v;
        const unsigned int* vw1 = (const unsigned int*)&v1v;
#pragma unroll
        for (int i = 0; i < 4; i++) {
            Vt[sc * 8 + 2 * i][sr]      = (unsigned short)(vw0[i] & 0xffff);
            Vt[sc * 8 + 2 * i + 1][sr]  = (unsigned short)(vw0[i] >> 16);
            Vt[(sc + 4) * 8 + 2 * i][sr]     = (unsigned short)(vw1[i] & 0xffff);
            Vt[(sc + 4) * 8 + 2 * i + 1][sr] = (unsigned short)(vw1[i] >> 16);
        }
        __syncthreads();

        f32x4 Sf[4];
#pragma unroll
        for (int nf = 0; nf < 4; nf++) {
            short8 b0 = *(const short8*)&Ks[nf * 16 + l16][quad * 8];
            short8 b1 = *(const short8*)&Ks[nf * 16 + l16][32 + quad * 8];
            f32x4 a = (f32x4){0.f, 0.f, 0.f, 0.f};
            a = __builtin_amdgcn_mfma_f32_16x16x32_bf16(qa0, b0, a, 0, 0, 0);
            a = __builtin_amdgcn_mfma_f32_16x16x32_bf16(qa1, b1, a, 0, 0, 0);
            Sf[nf] = a;
        }
        bool kval[4];
#pragma unroll
        for (int nf = 0; nf < 4; nf++) kval[nf] = (keyok[nf * 16 + l16] != 0);
        float P_[4][4];
        float mt[4];
#pragma unroll
        for (int r = 0; r < 4; r++) {
            float mx = -3.4e38f;
#pragma unroll
            for (int nf = 0; nf < 4; nf++) {
                float sv = kval[nf] ? Sf[nf][r] * 0.125f : NEG_;
                P_[nf][r] = sv;
                mx = fmaxf(mx, sv);
            }
            mt[r] = mx;
        }
#pragma unroll
        for (int off = 1; off < 16; off <<= 1)
#pragma unroll
            for (int r = 0; r < 4; r++) mt[r] = fmaxf(mt[r], __shfl_xor(mt[r], off));
        float alpha[4], lt[4];
#pragma unroll
        for (int r = 0; r < 4; r++) {
            float mn = fmaxf(m_run[r], mt[r]);
            alpha[r] = __expf(m_run[r] - mn);
            m_run[r] = mn; lt[r] = 0.f;
        }
#pragma unroll
        for (int nf = 0; nf < 4; nf++)
#pragma unroll
            for (int r = 0; r < 4; r++) {
                float p = (P_[nf][r] > -1.0e8f) ? __expf(P_[nf][r] - m_run[r]) : 0.f;
                P_[nf][r] = p; lt[r] += p;
            }
#pragma unroll
        for (int off = 1; off < 16; off <<= 1)
#pragma unroll
            for (int r = 0; r < 4; r++) lt[r] += __shfl_xor(lt[r], off);
#pragma unroll
        for (int r = 0; r < 4; r++) l_run[r] = l_run[r] * alpha[r] + lt[r];
#pragma unroll
        for (int nf = 0; nf < 4; nf++) {
            O[nf][0] *= alpha[0]; O[nf][1] *= alpha[1];
            O[nf][2] *= alpha[2]; O[nf][3] *= alpha[3];
        }
#pragma unroll
        for (int nf = 0; nf < 4; nf++)
#pragma unroll
            for (int r = 0; r < 4; r++)
                Ps[wave * 16 + quad * 4 + r][nf * 16 + l16] = f2bfu(P_[nf][r]);
#pragma unroll
        for (int hh = 0; hh < 2; hh++) {
            short8 pa = *(const short8*)&Ps[wave * 16 + l16][hh * 32 + quad * 8];
#pragma unroll
            for (int nf = 0; nf < 4; nf++) {
                short8 vb8 = *(const short8*)&Vt[nf * 16 + l16][hh * 32 + quad * 8];
                O[nf] = __builtin_amdgcn_mfma_f32_16x16x32_bf16(pa, vb8, O[nf], 0, 0, 0);
            }
        }
        __syncthreads();
    }
    size_t bhc = ((size_t)(b * H_ + h)) * NC_ + c;
#pragma unroll
    for (int r = 0; r < 4; r++) {
        int row = wave * 16 + quad * 4 + r;
#pragma unroll
        for (int nf = 0; nf < 4; nf++)
            Opart[bhc * (G_ * DH_) + (size_t)row * DH_ + nf * 16 + l16] = O[nf][r];
        if (l16 == 0) {
            mbuf[bhc * G_ + row] = m_run[r];
            lbuf[bhc * G_ + row] = l_run[r];
        }
    }
}

// ---------------- global attention pass 2: combine partials, write Tb rows ----------------
__global__ __launch_bounds__(64) void k_gattn_comb(
    const float* __restrict__ Opart, const float* __restrict__ mbuf,
    const float* __restrict__ lbuf, const int* __restrict__ idxg,
    unsigned short* __restrict__ Tb) {
    int g = blockIdx.x, h = blockIdx.y, b = blockIdx.z;
    int d = threadIdx.x;
    size_t bh = (size_t)(b * H_ + h);
    float M = -3.4e38f;
    float mv[NC_];
#pragma unroll
    for (int c = 0; c < NC_; c++) {
        mv[c] = mbuf[(bh * NC_ + c) * G_ + g];
        M = fmaxf(M, mv[c]);
    }
    float L = 0.f, o = 0.f;
#pragma unroll
    for (int c = 0; c < NC_; c++) {
        float e = __expf(mv[c] - M);
        L += lbuf[(bh * NC_ + c) * G_ + g] * e;
        o += Opart[(bh * NC_ + c) * (G_ * DH_) + (size_t)g * DH_ + d] * e;
    }
    int srow = idxg[b * G_ + g];
    Tb[((size_t)(b * S_ + srow)) * D_ + h * DH_ + d] = f2bfu(o / L);
}

// ---------------- VALU GEMM (small M): C = A(f32) @ B(f32) + bias ----------------
__global__ __launch_bounds__(256) void k_gemm(
    const float* __restrict__ A, const float* __restrict__ Bw,
    const float* __restrict__ bias, float* __restrict__ Cf,
    unsigned short* __restrict__ Cb, int M, int N, int K, int act) {
    __shared__ float As[16][68];
    __shared__ float Bs[16][68];
    int tl = threadIdx.x;
    int tx = tl & 15, ty = tl >> 4;
    int m0 = blockIdx.y << 6, n0 = blockIdx.x << 6;
    float c[4][4] = {{0.f}};
    int arow = tl >> 2, akk = (tl & 3) << 2;
    int bkk = tl >> 4, bcol = (tl & 15) << 2;
    for (int k0 = 0; k0 < K; k0 += 16) {
        float4 a4 = *(const float4*)(A + (size_t)(m0 + arow) * K + k0 + akk);
        As[akk + 0][arow] = a4.x; As[akk + 1][arow] = a4.y;
        As[akk + 2][arow] = a4.z; As[akk + 3][arow] = a4.w;
        float4 b4 = *(const float4*)(Bw + (size_t)(k0 + bkk) * N + n0 + bcol);
        Bs[bkk][bcol + 0] = b4.x; Bs[bkk][bcol + 1] = b4.y;
        Bs[bkk][bcol + 2] = b4.z; Bs[bkk][bcol + 3] = b4.w;
        __syncthreads();
#pragma unroll
        for (int kk = 0; kk < 16; kk++) {
            float4 av = *(const float4*)&As[kk][ty << 2];
            float4 bv = *(const float4*)&Bs[kk][tx << 2];
            float aa[4] = {av.x, av.y, av.z, av.w};
            float bb[4] = {bv.x, bv.y, bv.z, bv.w};
#pragma unroll
            for (int i = 0; i < 4; i++)
#pragma unroll
                for (int j = 0; j < 4; j++) c[i][j] += aa[i] * bb[j];
        }
        __syncthreads();
    }
    float bias4[4];
#pragma unroll
    for (int j = 0; j < 4; j++) bias4[j] = bias[n0 + (tx << 2) + j];
#pragma unroll
    for (int i = 0; i < 4; i++) {
        int mrow = m0 + (ty << 2) + i;
        float v0 = c[i][0] + bias4[0], v1 = c[i][1] + bias4[1];
        float v2 = c[i][2] + bias4[2], v3 = c[i][3] + bias4[3];
        if (act) { v0 = gelu_tanh(v0); v1 = gelu_tanh(v1); v2 = gelu_tanh(v2); v3 = gelu_tanh(v3); }
        if (Cf) {
            float4 o; o.x = v0; o.y = v1; o.z = v2; o.w = v3;
            *(float4*)(Cf + (size_t)mrow * N + n0 + (tx << 2)) = o;
        } else {
            ushort4 o; o.x = f2bfu(v0); o.y = f2bfu(v1); o.z = f2bfu(v2); o.w = f2bfu(v3);
            *(ushort4*)(Cb + (size_t)mrow * N + n0 + (tx << 2)) = o;
        }
    }
}

// ---------------- gather x rows at global indices ----------------
__global__ __launch_bounds__(256) void k_gather_xg(
    const float* __restrict__ x, const int* __restrict__ idxg, float* __restrict__ xg) {
    int bg = blockIdx.x;
    int b = bg / G_;
    int srow = idxg[bg];
    for (int d = threadIdx.x; d < D_; d += 256)
        xg[(size_t)bg * D_ + d] = x[((size_t)(b * S_ + srow)) * D_ + d];
}

// ---------------- classifier on core rows ----------------
__global__ __launch_bounds__(256) void k_classifier(
    const float* __restrict__ x, const float* __restrict__ Wc,
    const float* __restrict__ bc, const int* __restrict__ lo_p,
    int rows_pb, float* __restrict__ out) {
    int r = blockIdx.x;
    int b = r / rows_pb, i = r % rows_pb;
    int s = lo_p[0] + i;
    int t = threadIdx.x;
    __shared__ float xr[D_];
    __shared__ float red[256];
    const float* xrow = x + ((size_t)(b * S_ + s)) * D_;
    for (int d = t; d < D_; d += 256) xr[d] = xrow[d];
    __syncthreads();
    for (int c = 0; c < C_; c++) {
        float loc = 0.f;
        for (int d = t; d < D_; d += 256) loc += xr[d] * Wc[d * C_ + c];
        red[t] = loc; __syncthreads();
        for (int o = 128; o; o >>= 1) { if (t < o) red[t] += red[t + o]; __syncthreads(); }
        if (t == 0) out[r * C_ + c] = red[0] + bc[c];
        __syncthreads();
    }
}

extern "C" void kernel_launch(void* const* d_in, const int* in_sizes, int n_in,
                              void* d_out, int out_size, void* d_ws, size_t ws_size,
                              hipStream_t stream) {
    (void)in_sizes; (void)n_in; (void)ws_size;
    const float* emb_tok = (const float*)d_in[0];
    const float* emb_pos = (const float*)d_in[1];
    const float* ln_e_s = (const float*)d_in[2];
    const float* ln_e_b = (const float*)d_in[3];
    const float* Wq  = (const float*)d_in[4];
    const float* bq  = (const float*)d_in[5];
    const float* Wk  = (const float*)d_in[6];
    const float* bk  = (const float*)d_in[7];
    const float* Wv  = (const float*)d_in[8];
    const float* bv  = (const float*)d_in[9];
    const float* Wqg = (const float*)d_in[10];
    const float* bqg = (const float*)d_in[11];
    const float* Wkg = (const float*)d_in[12];
    const float* bkg = (const float*)d_in[13];
    const float* Wvg = (const float*)d_in[14];
    const float* bvg = (const float*)d_in[15];
    const float* Wo  = (const float*)d_in[16];
    const float* bo  = (const float*)d_in[17];
    const float* ln1_s = (const float*)d_in[18];
    const float* ln1_b = (const float*)d_in[19];
    const float* Wf1 = (const float*)d_in[20];
    const float* bf1 = (const float*)d_in[21];
    const float* Wf2 = (const float*)d_in[22];
    const float* bf2 = (const float*)d_in[23];
    const float* ln2_s = (const float*)d_in[24];
    const float* ln2_b = (const float*)d_in[25];
    const float* Wc  = (const float*)d_in[26];
    const float* bc  = (const float*)d_in[27];
    const int* input_ids = (const int*)d_in[28];
    const int* attn_mask = (const int*)d_in[29];
    const int* lo        = (const int*)d_in[30];

    const size_t SZB = (size_t)B_ * S_ * D_;   // 6291456 (byte unit)
    uint8_t* w = (uint8_t*)d_ws;
    float*          x    = (float*)w;                        // fp32  [0,4)
    unsigned short* xb   = (unsigned short*)(w + 4 * SZB);   // bf16  [4,6)
    float*          P    = (float*)(w + 6 * SZB);            // fp32  [6,10)
    unsigned short* qb   = (unsigned short*)(w + 10 * SZB);  // bf16 head-major
    unsigned short* kb   = (unsigned short*)(w + 12 * SZB);
    unsigned short* vb   = (unsigned short*)(w + 14 * SZB);
    unsigned short* kgab = (unsigned short*)(w + 16 * SZB);
    unsigned short* vgab = (unsigned short*)(w + 18 * SZB);
    unsigned short* Hb   = (unsigned short*)(w + 10 * SZB);  // FFN hidden, overlays qb..kgab
    unsigned short* Tb   = (unsigned short*)(w + 20 * SZB);  // bf16 [B*S,D]
    float* xg = (float*)(w + 22 * SZB);
    unsigned short* qgb = (unsigned short*)(w + 22 * SZB + (size_t)B_ * G_ * D_ * 4);
    int* idxg = (int*)(w + 22 * SZB + (size_t)B_ * G_ * D_ * 4 + (size_t)B_ * G_ * D_ * 2);
    float* Opart = (float*)(w + 23 * SZB);                   // B*H*NC*G*DH fp32 = 6.3 MB
    float* mbuf  = (float*)(w + 23 * SZB + (size_t)B_ * H_ * NC_ * G_ * DH_ * 4);
    float* lbuf  = mbuf + (size_t)B_ * H_ * NC_ * G_;

    const int BS = B_ * S_;

    k_embed_ln<<<BS, 256, 0, stream>>>(input_ids, emb_tok, emb_pos, ln_e_s, ln_e_b, x, xb);
    k_idx<<<1, 64, 0, stream>>>(input_ids, idxg);

    dim3 g_d(D_ / 128, BS / 128);       // (6, 64)
    dim3 g_ff(FF_ / 128, BS / 128);     // (24, 64)
    dim3 g_qg(D_ / 64, (B_ * G_) / 64); // (12, 2) small VALU path

    for (int l = 0; l < L_; l++) {
        const float* Wq_l  = Wq  + (size_t)l * D_ * D_;
        const float* Wk_l  = Wk  + (size_t)l * D_ * D_;
        const float* Wv_l  = Wv  + (size_t)l * D_ * D_;
        const float* Wqg_l = Wqg + (size_t)l * D_ * D_;
        const float* Wkg_l = Wkg + (size_t)l * D_ * D_;
        const float* Wvg_l = Wvg + (size_t)l * D_ * D_;
        const float* Wo_l  = Wo  + (size_t)l * D_ * D_;
        const float* Wf1_l = Wf1 + (size_t)l * D_ * FF_;
        const float* Wf2_l = Wf2 + (size_t)l * FF_ * D_;

        k_gemm_mfma<<<g_d, 256, 0, stream>>>(xb, Wq_l, bq + l * D_, nullptr, qb, BS, D_, D_, 0, 1);
        k_gemm_mfma<<<g_d, 256, 0, stream>>>(xb, Wk_l, bk + l * D_, nullptr, kb, BS, D_, D_, 0, 1);
        k_gemm_mfma<<<g_d, 256, 0, stream>>>(xb, Wv_l, bv + l * D_, nullptr, vb, BS, D_, D_, 0, 1);
        k_gemm_mfma<<<g_d, 256, 0, stream>>>(xb, Wkg_l, bkg + l * D_, nullptr, kgab, BS, D_, D_, 0, 1);
        k_gemm_mfma<<<g_d, 256, 0, stream>>>(xb, Wvg_l, bvg + l * D_, nullptr, vgab, BS, D_, D_, 0, 1);
        k_lattn<<<dim3(S_ / 64, H_, B_), 256, 0, stream>>>(qb, kb, vb, input_ids, attn_mask, idxg, Tb);
        k_gather_xg<<<B_ * G_, 256, 0, stream>>>(x, idxg, xg);
        k_gemm<<<g_qg, 256, 0, stream>>>(xg, Wqg_l, bqg + l * D_, nullptr, qgb, B_ * G_, D_, D_, 0);
        k_gattn_part<<<dim3(NC_, H_, B_), 256, 0, stream>>>(qgb, kgab, vgab, attn_mask, Opart, mbuf, lbuf);
        k_gattn_comb<<<dim3(G_, H_, B_), 64, 0, stream>>>(Opart, mbuf, lbuf, idxg, Tb);
        k_gemm_mfma<<<g_d, 256, 0, stream>>>(Tb, Wo_l, bo + l * D_, P, nullptr, BS, D_, D_, 0, 0);
        k_add_ln<<<BS, 256, 0, stream>>>(x, P, ln1_s + l * D_, ln1_b + l * D_, xb);
        k_gemm_mfma<<<g_ff, 256, 0, stream>>>(xb, Wf1_l, bf1 + l * FF_, nullptr, Hb, BS, FF_, D_, 1, 0);
        k_gemm_mfma<<<g_d, 256, 0, stream>>>(Hb, Wf2_l, bf2 + l * D_, P, nullptr, BS, D_, FF_, 0, 0);
        k_add_ln<<<BS, 256, 0, stream>>>(x, P, ln2_s + l * D_, ln2_b + l * D_, xb);
    }

    int rows = out_size / C_;
    int rows_pb = rows / B_;
    k_classifier<<<rows, 256, 0, stream>>>(x, Wc, bc, lo, rows_pb, (float*)d_out);
}

// Round 5
// 1388.878 us; speedup vs baseline: 9.3060x; 1.3544x over previous
//
#include <hip/hip_runtime.h>
#include <hip/hip_bf16.h>
#include <stdint.h>

#define B_ 2
#define S_ 4096
#define D_ 768
#define H_ 12
#define DH_ 64
#define L_ 2
#define W_ 256
#define G_ 64
#define FF_ 3072
#define C_ 7
#define SEP_ 2
#define NEG_ (-1000000000.0f)
#define NC_ 16          // key chunks for global attention (4096/256)

typedef __attribute__((ext_vector_type(8))) short short8;   // 8 bf16 (4 VGPRs)
typedef __attribute__((ext_vector_type(4))) float f32x4;    // 4 fp32 acc

__device__ __forceinline__ float bfu2f(unsigned short u) {
    return __uint_as_float(((unsigned int)u) << 16);
}
__device__ __forceinline__ unsigned short f2bfu(float f) {
    unsigned int x = __float_as_uint(f);
    unsigned int r = (x + 0x7fffu + ((x >> 16) & 1u)) >> 16;
    return (unsigned short)r;
}
__device__ __forceinline__ float gelu_tanh(float v) {
    float c = 0.7978845608028654f * (v + 0.044715f * v * v * v);
    return 0.5f * v * (1.0f + tanhf(c));
}

// ---------------- embedding + LN: one wave per row ----------------
__global__ __launch_bounds__(256) void k_embed_ln(
    const int* __restrict__ ids, const float* __restrict__ etok,
    const float* __restrict__ epos, const float* __restrict__ lns,
    const float* __restrict__ lnb, float* __restrict__ x,
    unsigned short* __restrict__ xb) {
    int row = (blockIdx.x << 2) + (threadIdx.x >> 6);
    int lane = threadIdx.x & 63;
    int s = row & (S_ - 1);
    int id = ids[row];
    const float4* ep = (const float4*)(etok + (size_t)id * D_);
    const float4* pp = (const float4*)(epos + (size_t)s * D_);
    float4 a[3];
    float sum = 0.f, sum2 = 0.f;
#pragma unroll
    for (int i = 0; i < 3; i++) {
        float4 ev = ep[lane + i * 64];
        float4 pv = pp[lane + i * 64];
        ev.x += pv.x; ev.y += pv.y; ev.z += pv.z; ev.w += pv.w;
        a[i] = ev;
        sum  += ev.x + ev.y + ev.z + ev.w;
        sum2 += ev.x * ev.x + ev.y * ev.y + ev.z * ev.z + ev.w * ev.w;
    }
#pragma unroll
    for (int off = 1; off < 64; off <<= 1) {
        sum += __shfl_xor(sum, off);
        sum2 += __shfl_xor(sum2, off);
    }
    float mean = sum * (1.0f / D_);
    float var = sum2 * (1.0f / D_) - mean * mean;
    float rs = rsqrtf(var + 1e-5f);
    float4* xp = (float4*)(x + (size_t)row * D_);
#pragma unroll
    for (int i = 0; i < 3; i++) {
        float4 g = *(const float4*)(lns + lane * 4 + i * 256);
        float4 bb = *(const float4*)(lnb + lane * 4 + i * 256);
        float4 v;
        v.x = (a[i].x - mean) * rs * g.x + bb.x;
        v.y = (a[i].y - mean) * rs * g.y + bb.y;
        v.z = (a[i].z - mean) * rs * g.z + bb.z;
        v.w = (a[i].w - mean) * rs * g.w + bb.w;
        xp[lane + i * 64] = v;
        ushort4 u; u.x = f2bfu(v.x); u.y = f2bfu(v.y); u.z = f2bfu(v.z); u.w = f2bfu(v.w);
        *(ushort4*)(xb + (size_t)row * D_ + lane * 4 + i * 256) = u;
    }
}

// ---------------- residual add + LN: one wave per row ----------------
__global__ __launch_bounds__(256) void k_add_ln(
    float* __restrict__ x, const float* __restrict__ y,
    const float* __restrict__ lns, const float* __restrict__ lnb,
    unsigned short* __restrict__ xb) {
    int row = (blockIdx.x << 2) + (threadIdx.x >> 6);
    int lane = threadIdx.x & 63;
    float4* xp = (float4*)(x + (size_t)row * D_);
    const float4* yp = (const float4*)(y + (size_t)row * D_);
    float4 a[3];
    float sum = 0.f, sum2 = 0.f;
#pragma unroll
    for (int i = 0; i < 3; i++) {
        float4 xv = xp[lane + i * 64];
        float4 yv = yp[lane + i * 64];
        xv.x += yv.x; xv.y += yv.y; xv.z += yv.z; xv.w += yv.w;
        a[i] = xv;
        sum  += xv.x + xv.y + xv.z + xv.w;
        sum2 += xv.x * xv.x + xv.y * xv.y + xv.z * xv.z + xv.w * xv.w;
    }
#pragma unroll
    for (int off = 1; off < 64; off <<= 1) {
        sum += __shfl_xor(sum, off);
        sum2 += __shfl_xor(sum2, off);
    }
    float mean = sum * (1.0f / D_);
    float var = sum2 * (1.0f / D_) - mean * mean;
    float rs = rsqrtf(var + 1e-5f);
#pragma unroll
    for (int i = 0; i < 3; i++) {
        float4 g = *(const float4*)(lns + lane * 4 + i * 256);
        float4 bb = *(const float4*)(lnb + lane * 4 + i * 256);
        float4 v;
        v.x = (a[i].x - mean) * rs * g.x + bb.x;
        v.y = (a[i].y - mean) * rs * g.y + bb.y;
        v.z = (a[i].z - mean) * rs * g.z + bb.z;
        v.w = (a[i].w - mean) * rs * g.w + bb.w;
        xp[lane + i * 64] = v;
        ushort4 u; u.x = f2bfu(v.x); u.y = f2bfu(v.y); u.z = f2bfu(v.z); u.w = f2bfu(v.w);
        *(ushort4*)(xb + (size_t)row * D_ + lane * 4 + i * 256) = u;
    }
}

// ---------------- global-token index extraction (parallel compaction) ----------------
__global__ __launch_bounds__(256) void k_idx(const int* __restrict__ ids, int* __restrict__ idxg) {
    int b = blockIdx.x;
    int t = threadIdx.x;
    __shared__ int cnt[256];
    __shared__ int totsh;
    int loc[16];
    int n = 0;
#pragma unroll
    for (int i = 0; i < 16; i++) {
        int s = t * 16 + i;
        if (s == 0 || ids[b * S_ + s] == SEP_) loc[n++] = s;
    }
    cnt[t] = n;
    __syncthreads();
    int base = 0;
    for (int u = 0; u < t; u++) base += cnt[u];
    for (int i = 0; i < n; i++) {
        int o = base + i;
        if (o < G_) idxg[b * G_ + o] = loc[i];
    }
    if (t == 255) totsh = base + n;
    __syncthreads();
    if (t == 0)
        for (int o = totsh; o < G_; o++) idxg[b * G_ + o] = 0;
}

// ---------------- MFMA GEMM: C[M,N] = A[M,K](bf16) @ Bw[K,N](fp32->bf16) + bias ----------------
// 128x128 tile, BK=32, 4 waves, each wave 64x64. hm=1: bf16 out head-major [B,H,S,DH].
__global__ __launch_bounds__(256) void k_gemm_mfma(
    const unsigned short* __restrict__ A, const float* __restrict__ Bw,
    const float* __restrict__ bias, float* __restrict__ Cf,
    unsigned short* __restrict__ Cb, int M, int N, int K, int act, int hm) {
    __shared__ unsigned short As[128][40];
    __shared__ unsigned short Bs[128][40];   // transposed: Bs[n][k]
    int t = threadIdx.x;
    int wave = t >> 6, lane = t & 63, l16 = lane & 15, quad = lane >> 4;
    int m0 = blockIdx.y << 7, n0 = blockIdx.x << 7;
    int wm = (wave >> 1) << 6, wn = (wave & 1) << 6;
    f32x4 acc[4][4];
#pragma unroll
    for (int i = 0; i < 4; i++)
#pragma unroll
        for (int j = 0; j < 4; j++) acc[i][j] = (f32x4){0.f, 0.f, 0.f, 0.f};

    int ar = t >> 1, akc = (t & 1) << 4;
    int bn = t & 127, bkh = (t >> 7) << 4;

    for (int k0 = 0; k0 < K; k0 += 32) {
        const unsigned short* ap = A + (size_t)(m0 + ar) * K + k0 + akc;
        uint4 a0 = *(const uint4*)ap;
        uint4 a1 = *(const uint4*)(ap + 8);
        *(uint4*)&As[ar][akc] = a0;
        *(uint4*)&As[ar][akc + 8] = a1;
        const float* bp = Bw + (size_t)(k0 + bkh) * N + n0 + bn;
        unsigned int pk[8];
#pragma unroll
        for (int i = 0; i < 8; i++) {
            unsigned int lo = f2bfu(bp[(size_t)(2 * i) * N]);
            unsigned int hi = f2bfu(bp[(size_t)(2 * i + 1) * N]);
            pk[i] = lo | (hi << 16);
        }
        *(uint4*)&Bs[bn][bkh] = *(uint4*)&pk[0];
        *(uint4*)&Bs[bn][bkh + 8] = *(uint4*)&pk[4];
        __syncthreads();
        short8 af[4], bf[4];
#pragma unroll
        for (int i = 0; i < 4; i++) af[i] = *(const short8*)&As[wm + i * 16 + l16][quad * 8];
#pragma unroll
        for (int j = 0; j < 4; j++) bf[j] = *(const short8*)&Bs[wn + j * 16 + l16][quad * 8];
#pragma unroll
        for (int i = 0; i < 4; i++)
#pragma unroll
            for (int j = 0; j < 4; j++)
                acc[i][j] = __builtin_amdgcn_mfma_f32_16x16x32_bf16(af[i], bf[j], acc[i][j], 0, 0, 0);
        __syncthreads();
    }
    float bj[4];
#pragma unroll
    for (int j = 0; j < 4; j++) bj[j] = bias[n0 + wn + j * 16 + l16];
#pragma unroll
    for (int i = 0; i < 4; i++)
#pragma unroll
        for (int j = 0; j < 4; j++) {
            int col = n0 + wn + j * 16 + l16;
#pragma unroll
            for (int r = 0; r < 4; r++) {
                int row = m0 + wm + i * 16 + quad * 4 + r;
                float v = acc[i][j][r] + bj[j];
                if (act) v = gelu_tanh(v);
                if (Cf) {
                    Cf[(size_t)row * N + col] = v;
                } else if (hm) {
                    size_t adr = ((((size_t)(row >> 12)) * H_ + (col >> 6)) * S_ +
                                  (row & (S_ - 1))) * DH_ + (col & 63);
                    Cb[adr] = f2bfu(v);
                } else {
                    Cb[(size_t)row * N + col] = f2bfu(v);
                }
            }
        }
}

// ---------------- fused 5-way projection GEMM (q,k,v,kg,vg), head-major bf16 out ----------------
struct P5 {
    const float* W[5];
    const float* bias[5];
    unsigned short* out[5];
};
__global__ __launch_bounds__(256) void k_gemm_qkv5(
    const unsigned short* __restrict__ A, P5 p) {
    __shared__ unsigned short As[128][40];
    __shared__ unsigned short Bs[128][40];
    const float* __restrict__ Bw = p.W[blockIdx.z];
    const float* __restrict__ bias = p.bias[blockIdx.z];
    unsigned short* __restrict__ Cb = p.out[blockIdx.z];
    const int N = D_, K = D_;
    int t = threadIdx.x;
    int wave = t >> 6, lane = t & 63, l16 = lane & 15, quad = lane >> 4;
    int m0 = blockIdx.y << 7, n0 = blockIdx.x << 7;
    int wm = (wave >> 1) << 6, wn = (wave & 1) << 6;
    f32x4 acc[4][4];
#pragma unroll
    for (int i = 0; i < 4; i++)
#pragma unroll
        for (int j = 0; j < 4; j++) acc[i][j] = (f32x4){0.f, 0.f, 0.f, 0.f};

    int ar = t >> 1, akc = (t & 1) << 4;
    int bn = t & 127, bkh = (t >> 7) << 4;

    for (int k0 = 0; k0 < K; k0 += 32) {
        const unsigned short* ap = A + (size_t)(m0 + ar) * K + k0 + akc;
        uint4 a0 = *(const uint4*)ap;
        uint4 a1 = *(const uint4*)(ap + 8);
        *(uint4*)&As[ar][akc] = a0;
        *(uint4*)&As[ar][akc + 8] = a1;
        const float* bp = Bw + (size_t)(k0 + bkh) * N + n0 + bn;
        unsigned int pk[8];
#pragma unroll
        for (int i = 0; i < 8; i++) {
            unsigned int lo = f2bfu(bp[(size_t)(2 * i) * N]);
            unsigned int hi = f2bfu(bp[(size_t)(2 * i + 1) * N]);
            pk[i] = lo | (hi << 16);
        }
        *(uint4*)&Bs[bn][bkh] = *(uint4*)&pk[0];
        *(uint4*)&Bs[bn][bkh + 8] = *(uint4*)&pk[4];
        __syncthreads();
        short8 af[4], bf[4];
#pragma unroll
        for (int i = 0; i < 4; i++) af[i] = *(const short8*)&As[wm + i * 16 + l16][quad * 8];
#pragma unroll
        for (int j = 0; j < 4; j++) bf[j] = *(const short8*)&Bs[wn + j * 16 + l16][quad * 8];
#pragma unroll
        for (int i = 0; i < 4; i++)
#pragma unroll
            for (int j = 0; j < 4; j++)
                acc[i][j] = __builtin_amdgcn_mfma_f32_16x16x32_bf16(af[i], bf[j], acc[i][j], 0, 0, 0);
        __syncthreads();
    }
    float bj[4];
#pragma unroll
    for (int j = 0; j < 4; j++) bj[j] = bias[n0 + wn + j * 16 + l16];
#pragma unroll
    for (int i = 0; i < 4; i++)
#pragma unroll
        for (int j = 0; j < 4; j++) {
            int col = n0 + wn + j * 16 + l16;
#pragma unroll
            for (int r = 0; r < 4; r++) {
                int row = m0 + wm + i * 16 + quad * 4 + r;
                float v = acc[i][j][r] + bj[j];
                size_t adr = ((((size_t)(row >> 12)) * H_ + (col >> 6)) * S_ +
                              (row & (S_ - 1))) * DH_ + (col & 63);
                Cb[adr] = f2bfu(v);
            }
        }
}

// ---------------- MFMA flash local attention: block = (64 queries, h, b) ----------------
__global__ __launch_bounds__(256) void k_lattn(
    const unsigned short* __restrict__ q, const unsigned short* __restrict__ k,
    const unsigned short* __restrict__ v, const int* __restrict__ ids,
    const int* __restrict__ am, const int* __restrict__ idxg,
    unsigned short* __restrict__ Tb) {
    int s0 = blockIdx.x << 6, h = blockIdx.y, b = blockIdx.z;
    int t = threadIdx.x;
    int wave = t >> 6, lane = t & 63, l16 = lane & 15, quad = lane >> 4;

    __shared__ unsigned short Ks[64][72];
    __shared__ unsigned short Vt[64][72];
    __shared__ unsigned short Ps[64][72];
    __shared__ unsigned char keyok[64];

    const size_t headbase = (((size_t)b * H_) + h) * S_;
    int qrow = s0 + wave * 16 + l16;
    const unsigned short* qptr = q + (headbase + qrow) * DH_;
    short8 qa0 = *(const short8*)(qptr + quad * 8);
    short8 qa1 = *(const short8*)(qptr + 32 + quad * 8);

    f32x4 O[4];
#pragma unroll
    for (int nf = 0; nf < 4; nf++) O[nf] = (f32x4){0.f, 0.f, 0.f, 0.f};
    float m_run[4] = {-3.4e38f, -3.4e38f, -3.4e38f, -3.4e38f};
    float l_run[4] = {0.f, 0.f, 0.f, 0.f};

    int kbase = s0 - 256;
    int sr = t >> 2, sc = t & 3;

    for (int tile = 0; tile < 10; tile++) {
        int sK, sclamp; bool okf;
        if (tile < 9) {
            sK = kbase + tile * 64 + sr;
            bool inr = (sK >= 0) && (sK < S_);
            sclamp = inr ? sK : 0;
            okf = inr && (am[b * S_ + sclamp] != 0) &&
                  !((ids[b * S_ + sclamp] == SEP_) || (sK == 0));
        } else {
            sK = idxg[b * G_ + sr];
            sclamp = sK; okf = true;
        }
        if (sc == 0) keyok[sr] = okf ? 1 : 0;
        const unsigned short* srcK = k + (headbase + sclamp) * DH_;
        const unsigned short* srcV = v + (headbase + sclamp) * DH_;
        uint4 k0v = *(const uint4*)(srcK + sc * 8);
        uint4 k1v = *(const uint4*)(srcK + (sc + 4) * 8);
        uint4 v0v = *(const uint4*)(srcV + sc * 8);
        uint4 v1v = *(const uint4*)(srcV + (sc + 4) * 8);
        *(uint4*)&Ks[sr][sc * 8] = k0v;
        *(uint4*)&Ks[sr][(sc + 4) * 8] = k1v;
        const unsigned int* vw0 = (const unsigned int*)&v0v;
        const unsigned int* vw1 = (const unsigned int*)&v1v;
#pragma unroll
        for (int i = 0; i < 4; i++) {
            Vt[sc * 8 + 2 * i][sr]      = (unsigned short)(vw0[i] & 0xffff);
            Vt[sc * 8 + 2 * i + 1][sr]  = (unsigned short)(vw0[i] >> 16);
            Vt[(sc + 4) * 8 + 2 * i][sr]     = (unsigned short)(vw1[i] & 0xffff);
            Vt[(sc + 4) * 8 + 2 * i + 1][sr] = (unsigned short)(vw1[i] >> 16);
        }
        __syncthreads();

        f32x4 Sf[4];
#pragma unroll
        for (int nf = 0; nf < 4; nf++) {
            short8 b0 = *(const short8*)&Ks[nf * 16 + l16][quad * 8];
            short8 b1 = *(const short8*)&Ks[nf * 16 + l16][32 + quad * 8];
            f32x4 a = (f32x4){0.f, 0.f, 0.f, 0.f};
            a = __builtin_amdgcn_mfma_f32_16x16x32_bf16(qa0, b0, a, 0, 0, 0);
            a = __builtin_amdgcn_mfma_f32_16x16x32_bf16(qa1, b1, a, 0, 0, 0);
            Sf[nf] = a;
        }
        int ktb = kbase + tile * 64;
        bool kval[4];
#pragma unroll
        for (int nf = 0; nf < 4; nf++) kval[nf] = (tile == 9) || (keyok[nf * 16 + l16] != 0);
        float P_[4][4];
        float mt[4];
#pragma unroll
        for (int r = 0; r < 4; r++) {
            int qs = s0 + wave * 16 + quad * 4 + r;
            float mx = -3.4e38f;
#pragma unroll
            for (int nf = 0; nf < 4; nf++) {
                int ks2 = ktb + nf * 16 + l16;
                bool ok = kval[nf] && ((tile == 9) || (ks2 >= qs - 256 && ks2 <= qs + 256));
                float sv = ok ? Sf[nf][r] * 0.125f : NEG_;
                P_[nf][r] = sv;
                mx = fmaxf(mx, sv);
            }
            mt[r] = mx;
        }
#pragma unroll
        for (int off = 1; off < 16; off <<= 1)
#pragma unroll
            for (int r = 0; r < 4; r++) mt[r] = fmaxf(mt[r], __shfl_xor(mt[r], off));
        float alpha[4], lt[4];
#pragma unroll
        for (int r = 0; r < 4; r++) {
            float mn = fmaxf(m_run[r], mt[r]);
            alpha[r] = __expf(m_run[r] - mn);
            m_run[r] = mn; lt[r] = 0.f;
        }
#pragma unroll
        for (int nf = 0; nf < 4; nf++)
#pragma unroll
            for (int r = 0; r < 4; r++) {
                float p = (P_[nf][r] > -1.0e8f) ? __expf(P_[nf][r] - m_run[r]) : 0.f;
                P_[nf][r] = p; lt[r] += p;
            }
#pragma unroll
        for (int off = 1; off < 16; off <<= 1)
#pragma unroll
            for (int r = 0; r < 4; r++) lt[r] += __shfl_xor(lt[r], off);
#pragma unroll
        for (int r = 0; r < 4; r++) l_run[r] = l_run[r] * alpha[r] + lt[r];
#pragma unroll
        for (int nf = 0; nf < 4; nf++) {
            O[nf][0] *= alpha[0]; O[nf][1] *= alpha[1];
            O[nf][2] *= alpha[2]; O[nf][3] *= alpha[3];
        }
#pragma unroll
        for (int nf = 0; nf < 4; nf++)
#pragma unroll
            for (int r = 0; r < 4; r++)
                Ps[wave * 16 + quad * 4 + r][nf * 16 + l16] = f2bfu(P_[nf][r]);
#pragma unroll
        for (int hh = 0; hh < 2; hh++) {
            short8 pa = *(const short8*)&Ps[wave * 16 + l16][hh * 32 + quad * 8];
#pragma unroll
            for (int nf = 0; nf < 4; nf++) {
                short8 vb8 = *(const short8*)&Vt[nf * 16 + l16][hh * 32 + quad * 8];
                O[nf] = __builtin_amdgcn_mfma_f32_16x16x32_bf16(pa, vb8, O[nf], 0, 0, 0);
            }
        }
        __syncthreads();
    }
#pragma unroll
    for (int r = 0; r < 4; r++) {
        int qs = s0 + wave * 16 + quad * 4 + r;
        float invl = 1.0f / l_run[r];
        size_t base = ((size_t)(b * S_ + qs)) * D_ + h * DH_;
#pragma unroll
        for (int nf = 0; nf < 4; nf++)
            Tb[base + nf * 16 + l16] = f2bfu(O[nf][r] * invl);
    }
}

// ---------------- MFMA global-query attention, pass 1 ----------------
__global__ __launch_bounds__(256) void k_gattn_part(
    const unsigned short* __restrict__ qg, const unsigned short* __restrict__ kga,
    const unsigned short* __restrict__ vga, const int* __restrict__ am,
    float* __restrict__ Opart, float* __restrict__ mbuf, float* __restrict__ lbuf) {
    int c = blockIdx.x, h = blockIdx.y, b = blockIdx.z;
    int t = threadIdx.x;
    int wave = t >> 6, lane = t & 63, l16 = lane & 15, quad = lane >> 4;

    __shared__ unsigned short Ks[64][72];
    __shared__ unsigned short Vt[64][72];
    __shared__ unsigned short Ps[64][72];
    __shared__ unsigned char keyok[64];

    const size_t headbase = (((size_t)b * H_) + h) * S_;
    int grow = wave * 16 + l16;
    const unsigned short* qptr = qg + ((size_t)(b * G_ + grow)) * D_ + h * DH_;
    short8 qa0 = *(const short8*)(qptr + quad * 8);
    short8 qa1 = *(const short8*)(qptr + 32 + quad * 8);

    f32x4 O[4];
#pragma unroll
    for (int nf = 0; nf < 4; nf++) O[nf] = (f32x4){0.f, 0.f, 0.f, 0.f};
    float m_run[4] = {-3.4e38f, -3.4e38f, -3.4e38f, -3.4e38f};
    float l_run[4] = {0.f, 0.f, 0.f, 0.f};

    int kbase = c * 256;
    int sr = t >> 2, sc = t & 3;

    for (int tile = 0; tile < 4; tile++) {
        int sK = kbase + tile * 64 + sr;
        if (sc == 0) keyok[sr] = (am[b * S_ + sK] != 0) ? 1 : 0;
        const unsigned short* srcK = kga + (headbase + sK) * DH_;
        const unsigned short* srcV = vga + (headbase + sK) * DH_;
        uint4 k0v = *(const uint4*)(srcK + sc * 8);
        uint4 k1v = *(const uint4*)(srcK + (sc + 4) * 8);
        uint4 v0v = *(const uint4*)(srcV + sc * 8);
        uint4 v1v = *(const uint4*)(srcV + (sc + 4) * 8);
        *(uint4*)&Ks[sr][sc * 8] = k0v;
        *(uint4*)&Ks[sr][(sc + 4) * 8] = k1v;
        const unsigned int* vw0 = (const unsigned int*)&v0v;
        const unsigned int* vw1 = (const unsigned int*)&v1v;
#pragma unroll
        for (int i = 0; i < 4; i++) {
            Vt[sc * 8 + 2 * i][sr]      = (unsigned short)(vw0[i] & 0xffff);
            Vt[sc * 8 + 2 * i + 1][sr]  = (unsigned short)(vw0[i] >> 16);
            Vt[(sc + 4) * 8 + 2 * i][sr]     = (unsigned short)(vw1[i] & 0xffff);
            Vt[(sc + 4) * 8 + 2 * i + 1][sr] = (unsigned short)(vw1[i] >> 16);
        }
        __syncthreads();

        f32x4 Sf[4];
#pragma unroll
        for (int nf = 0; nf < 4; nf++) {
            short8 b0 = *(const short8*)&Ks[nf * 16 + l16][quad * 8];
            short8 b1 = *(const short8*)&Ks[nf * 16 + l16][32 + quad * 8];
            f32x4 a = (f32x4){0.f, 0.f, 0.f, 0.f};
            a = __builtin_amdgcn_mfma_f32_16x16x32_bf16(qa0, b0, a, 0, 0, 0);
            a = __builtin_amdgcn_mfma_f32_16x16x32_bf16(qa1, b1, a, 0, 0, 0);
            Sf[nf] = a;
        }
        bool kval[4];
#pragma unroll
        for (int nf = 0; nf < 4; nf++) kval[nf] = (keyok[nf * 16 + l16] != 0);
        float P_[4][4];
        float mt[4];
#pragma unroll
        for (int r = 0; r < 4; r++) {
            float mx = -3.4e38f;
#pragma unroll
            for (int nf = 0; nf < 4; nf++) {
                float sv = kval[nf] ? Sf[nf][r] * 0.125f : NEG_;
                P_[nf][r] = sv;
                mx = fmaxf(mx, sv);
            }
            mt[r] = mx;
        }
#pragma unroll
        for (int off = 1; off < 16; off <<= 1)
#pragma unroll
            for (int r = 0; r < 4; r++) mt[r] = fmaxf(mt[r], __shfl_xor(mt[r], off));
        float alpha[4], lt[4];
#pragma unroll
        for (int r = 0; r < 4; r++) {
            float mn = fmaxf(m_run[r], mt[r]);
            alpha[r] = __expf(m_run[r] - mn);
            m_run[r] = mn; lt[r] = 0.f;
        }
#pragma unroll
        for (int nf = 0; nf < 4; nf++)
#pragma unroll
            for (int r = 0; r < 4; r++) {
                float p = (P_[nf][r] > -1.0e8f) ? __expf(P_[nf][r] - m_run[r]) : 0.f;
                P_[nf][r] = p; lt[r] += p;
            }
#pragma unroll
        for (int off = 1; off < 16; off <<= 1)
#pragma unroll
            for (int r = 0; r < 4; r++) lt[r] += __shfl_xor(lt[r], off);
#pragma unroll
        for (int r = 0; r < 4; r++) l_run[r] = l_run[r] * alpha[r] + lt[r];
#pragma unroll
        for (int nf = 0; nf < 4; nf++) {
            O[nf][0] *= alpha[0]; O[nf][1] *= alpha[1];
            O[nf][2] *= alpha[2]; O[nf][3] *= alpha[3];
        }
#pragma unroll
        for (int nf = 0; nf < 4; nf++)
#pragma unroll
            for (int r = 0; r < 4; r++)
                Ps[wave * 16 + quad * 4 + r][nf * 16 + l16] = f2bfu(P_[nf][r]);
#pragma unroll
        for (int hh = 0; hh < 2; hh++) {
            short8 pa = *(const short8*)&Ps[wave * 16 + l16][hh * 32 + quad * 8];
#pragma unroll
            for (int nf = 0; nf < 4; nf++) {
                short8 vb8 = *(const short8*)&Vt[nf * 16 + l16][hh * 32 + quad * 8];
                O[nf] = __builtin_amdgcn_mfma_f32_16x16x32_bf16(pa, vb8, O[nf], 0, 0, 0);
            }
        }
        __syncthreads();
    }
    size_t bhc = ((size_t)(b * H_ + h)) * NC_ + c;
#pragma unroll
    for (int r = 0; r < 4; r++) {
        int row = wave * 16 + quad * 4 + r;
#pragma unroll
        for (int nf = 0; nf < 4; nf++)
            Opart[bhc * (G_ * DH_) + (size_t)row * DH_ + nf * 16 + l16] = O[nf][r];
        if (l16 == 0) {
            mbuf[bhc * G_ + row] = m_run[r];
            lbuf[bhc * G_ + row] = l_run[r];
        }
    }
}

// ---------------- global attention pass 2: combine partials ----------------
__global__ __launch_bounds__(64) void k_gattn_comb(
    const float* __restrict__ Opart, const float* __restrict__ mbuf,
    const float* __restrict__ lbuf, const int* __restrict__ idxg,
    unsigned short* __restrict__ Tb) {
    int g = blockIdx.x, h = blockIdx.y, b = blockIdx.z;
    int d = threadIdx.x;
    size_t bh = (size_t)(b * H_ + h);
    float M = -3.4e38f;
    float mv[NC_];
#pragma unroll
    for (int c = 0; c < NC_; c++) {
        mv[c] = mbuf[(bh * NC_ + c) * G_ + g];
        M = fmaxf(M, mv[c]);
    }
    float L = 0.f, o = 0.f;
#pragma unroll
    for (int c = 0; c < NC_; c++) {
        float e = __expf(mv[c] - M);
        L += lbuf[(bh * NC_ + c) * G_ + g] * e;
        o += Opart[(bh * NC_ + c) * (G_ * DH_) + (size_t)g * DH_ + d] * e;
    }
    int srow = idxg[b * G_ + g];
    Tb[((size_t)(b * S_ + srow)) * D_ + h * DH_ + d] = f2bfu(o / L);
}

// ---------------- VALU GEMM (small M) ----------------
__global__ __launch_bounds__(256) void k_gemm(
    const float* __restrict__ A, const float* __restrict__ Bw,
    const float* __restrict__ bias, float* __restrict__ Cf,
    unsigned short* __restrict__ Cb, int M, int N, int K, int act) {
    __shared__ float As[16][68];
    __shared__ float Bs[16][68];
    int tl = threadIdx.x;
    int tx = tl & 15, ty = tl >> 4;
    int m0 = blockIdx.y << 6, n0 = blockIdx.x << 6;
    float c[4][4] = {{0.f}};
    int arow = tl >> 2, akk = (tl & 3) << 2;
    int bkk = tl >> 4, bcol = (tl & 15) << 2;
    for (int k0 = 0; k0 < K; k0 += 16) {
        float4 a4 = *(const float4*)(A + (size_t)(m0 + arow) * K + k0 + akk);
        As[akk + 0][arow] = a4.x; As[akk + 1][arow] = a4.y;
        As[akk + 2][arow] = a4.z; As[akk + 3][arow] = a4.w;
        float4 b4 = *(const float4*)(Bw + (size_t)(k0 + bkk) * N + n0 + bcol);
        Bs[bkk][bcol + 0] = b4.x; Bs[bkk][bcol + 1] = b4.y;
        Bs[bkk][bcol + 2] = b4.z; Bs[bkk][bcol + 3] = b4.w;
        __syncthreads();
#pragma unroll
        for (int kk = 0; kk < 16; kk++) {
            float4 av = *(const float4*)&As[kk][ty << 2];
            float4 bv = *(const float4*)&Bs[kk][tx << 2];
            float aa[4] = {av.x, av.y, av.z, av.w};
            float bb[4] = {bv.x, bv.y, bv.z, bv.w};
#pragma unroll
            for (int i = 0; i < 4; i++)
#pragma unroll
                for (int j = 0; j < 4; j++) c[i][j] += aa[i] * bb[j];
        }
        __syncthreads();
    }
    float bias4[4];
#pragma unroll
    for (int j = 0; j < 4; j++) bias4[j] = bias[n0 + (tx << 2) + j];
#pragma unroll
    for (int i = 0; i < 4; i++) {
        int mrow = m0 + (ty << 2) + i;
        float v0 = c[i][0] + bias4[0], v1 = c[i][1] + bias4[1];
        float v2 = c[i][2] + bias4[2], v3 = c[i][3] + bias4[3];
        if (act) { v0 = gelu_tanh(v0); v1 = gelu_tanh(v1); v2 = gelu_tanh(v2); v3 = gelu_tanh(v3); }
        if (Cf) {
            float4 o; o.x = v0; o.y = v1; o.z = v2; o.w = v3;
            *(float4*)(Cf + (size_t)mrow * N + n0 + (tx << 2)) = o;
        } else {
            ushort4 o; o.x = f2bfu(v0); o.y = f2bfu(v1); o.z = f2bfu(v2); o.w = f2bfu(v3);
            *(ushort4*)(Cb + (size_t)mrow * N + n0 + (tx << 2)) = o;
        }
    }
}

// ---------------- gather x rows at global indices ----------------
__global__ __launch_bounds__(256) void k_gather_xg(
    const float* __restrict__ x, const int* __restrict__ idxg, float* __restrict__ xg) {
    int bg = blockIdx.x;
    int b = bg / G_;
    int srow = idxg[bg];
    for (int d = threadIdx.x; d < D_; d += 256)
        xg[(size_t)bg * D_ + d] = x[((size_t)(b * S_ + srow)) * D_ + d];
}

// ---------------- classifier on core rows ----------------
__global__ __launch_bounds__(256) void k_classifier(
    const float* __restrict__ x, const float* __restrict__ Wc,
    const float* __restrict__ bc, const int* __restrict__ lo_p,
    int rows_pb, float* __restrict__ out) {
    int r = blockIdx.x;
    int b = r / rows_pb, i = r % rows_pb;
    int s = lo_p[0] + i;
    int t = threadIdx.x;
    __shared__ float xr[D_];
    __shared__ float red[256];
    const float* xrow = x + ((size_t)(b * S_ + s)) * D_;
    for (int d = t; d < D_; d += 256) xr[d] = xrow[d];
    __syncthreads();
    for (int c = 0; c < C_; c++) {
        float loc = 0.f;
        for (int d = t; d < D_; d += 256) loc += xr[d] * Wc[d * C_ + c];
        red[t] = loc; __syncthreads();
        for (int o = 128; o; o >>= 1) { if (t < o) red[t] += red[t + o]; __syncthreads(); }
        if (t == 0) out[r * C_ + c] = red[0] + bc[c];
        __syncthreads();
    }
}

extern "C" void kernel_launch(void* const* d_in, const int* in_sizes, int n_in,
                              void* d_out, int out_size, void* d_ws, size_t ws_size,
                              hipStream_t stream) {
    (void)in_sizes; (void)n_in; (void)ws_size;
    const float* emb_tok = (const float*)d_in[0];
    const float* emb_pos = (const float*)d_in[1];
    const float* ln_e_s = (const float*)d_in[2];
    const float* ln_e_b = (const float*)d_in[3];
    const float* Wq  = (const float*)d_in[4];
    const float* bq  = (const float*)d_in[5];
    const float* Wk  = (const float*)d_in[6];
    const float* bk  = (const float*)d_in[7];
    const float* Wv  = (const float*)d_in[8];
    const float* bv  = (const float*)d_in[9];
    const float* Wqg = (const float*)d_in[10];
    const float* bqg = (const float*)d_in[11];
    const float* Wkg = (const float*)d_in[12];
    const float* bkg = (const float*)d_in[13];
    const float* Wvg = (const float*)d_in[14];
    const float* bvg = (const float*)d_in[15];
    const float* Wo  = (const float*)d_in[16];
    const float* bo  = (const float*)d_in[17];
    const float* ln1_s = (const float*)d_in[18];
    const float* ln1_b = (const float*)d_in[19];
    const float* Wf1 = (const float*)d_in[20];
    const float* bf1 = (const float*)d_in[21];
    const float* Wf2 = (const float*)d_in[22];
    const float* bf2 = (const float*)d_in[23];
    const float* ln2_s = (const float*)d_in[24];
    const float* ln2_b = (const float*)d_in[25];
    const float* Wc  = (const float*)d_in[26];
    const float* bc  = (const float*)d_in[27];
    const int* input_ids = (const int*)d_in[28];
    const int* attn_mask = (const int*)d_in[29];
    const int* lo        = (const int*)d_in[30];

    const size_t SZB = (size_t)B_ * S_ * D_;
    uint8_t* w = (uint8_t*)d_ws;
    float*          x    = (float*)w;
    unsigned short* xb   = (unsigned short*)(w + 4 * SZB);
    float*          P    = (float*)(w + 6 * SZB);
    unsigned short* qb   = (unsigned short*)(w + 10 * SZB);
    unsigned short* kb   = (unsigned short*)(w + 12 * SZB);
    unsigned short* vb   = (unsigned short*)(w + 14 * SZB);
    unsigned short* kgab = (unsigned short*)(w + 16 * SZB);
    unsigned short* vgab = (unsigned short*)(w + 18 * SZB);
    unsigned short* Hb   = (unsigned short*)(w + 10 * SZB);
    unsigned short* Tb   = (unsigned short*)(w + 20 * SZB);
    float* xg = (float*)(w + 22 * SZB);
    unsigned short* qgb = (unsigned short*)(w + 22 * SZB + (size_t)B_ * G_ * D_ * 4);
    int* idxg = (int*)(w + 22 * SZB + (size_t)B_ * G_ * D_ * 4 + (size_t)B_ * G_ * D_ * 2);
    float* Opart = (float*)(w + 23 * SZB);
    float* mbuf  = (float*)(w + 23 * SZB + (size_t)B_ * H_ * NC_ * G_ * DH_ * 4);
    float* lbuf  = mbuf + (size_t)B_ * H_ * NC_ * G_;

    const int BS = B_ * S_;

    k_embed_ln<<<BS / 4, 256, 0, stream>>>(input_ids, emb_tok, emb_pos, ln_e_s, ln_e_b, x, xb);
    k_idx<<<B_, 256, 0, stream>>>(input_ids, idxg);

    dim3 g_d(D_ / 128, BS / 128);         // (6, 64)
    dim3 g_d5(D_ / 128, BS / 128, 5);     // fused projections
    dim3 g_ff(FF_ / 128, BS / 128);       // (24, 64)
    dim3 g_qg(D_ / 64, (B_ * G_) / 64);   // (12, 2)

    for (int l = 0; l < L_; l++) {
        P5 p5;
        p5.W[0] = Wq  + (size_t)l * D_ * D_;  p5.bias[0] = bq  + l * D_;  p5.out[0] = qb;
        p5.W[1] = Wk  + (size_t)l * D_ * D_;  p5.bias[1] = bk  + l * D_;  p5.out[1] = kb;
        p5.W[2] = Wv  + (size_t)l * D_ * D_;  p5.bias[2] = bv  + l * D_;  p5.out[2] = vb;
        p5.W[3] = Wkg + (size_t)l * D_ * D_;  p5.bias[3] = bkg + l * D_;  p5.out[3] = kgab;
        p5.W[4] = Wvg + (size_t)l * D_ * D_;  p5.bias[4] = bvg + l * D_;  p5.out[4] = vgab;
        const float* Wqg_l = Wqg + (size_t)l * D_ * D_;
        const float* Wo_l  = Wo  + (size_t)l * D_ * D_;
        const float* Wf1_l = Wf1 + (size_t)l * D_ * FF_;
        const float* Wf2_l = Wf2 + (size_t)l * FF_ * D_;

        k_gemm_qkv5<<<g_d5, 256, 0, stream>>>(xb, p5);
        k_lattn<<<dim3(S_ / 64, H_, B_), 256, 0, stream>>>(qb, kb, vb, input_ids, attn_mask, idxg, Tb);
        k_gather_xg<<<B_ * G_, 256, 0, stream>>>(x, idxg, xg);
        k_gemm<<<g_qg, 256, 0, stream>>>(xg, Wqg_l, bqg + l * D_, nullptr, qgb, B_ * G_, D_, D_, 0);
        k_gattn_part<<<dim3(NC_, H_, B_), 256, 0, stream>>>(qgb, kgab, vgab, attn_mask, Opart, mbuf, lbuf);
        k_gattn_comb<<<dim3(G_, H_, B_), 64, 0, stream>>>(Opart, mbuf, lbuf, idxg, Tb);
        k_gemm_mfma<<<g_d, 256, 0, stream>>>(Tb, Wo_l, bo + l * D_, P, nullptr, BS, D_, D_, 0, 0);
        k_add_ln<<<BS / 4, 256, 0, stream>>>(x, P, ln1_s + l * D_, ln1_b + l * D_, xb);
        k_gemm_mfma<<<g_ff, 256, 0, stream>>>(xb, Wf1_l, bf1 + l * FF_, nullptr, Hb, BS, FF_, D_, 1, 0);
        k_gemm_mfma<<<g_d, 256, 0, stream>>>(Hb, Wf2_l, bf2 + l * D_, P, nullptr, BS, D_, FF_, 0, 0);
        k_add_ln<<<BS / 4, 256, 0, stream>>>(x, P, ln2_s + l * D_, ln2_b + l * D_, xb);
    }

    int rows = out_size / C_;
    int rows_pb = rows / B_;
    k_classifier<<<rows, 256, 0, stream>>>(x, Wc, bc, lo, rows_pb, (float*)d_out);
}

// Round 6
// 1277.283 us; speedup vs baseline: 10.1191x; 1.0874x over previous
//
#include <hip/hip_runtime.h>
#include <hip/hip_bf16.h>
#include <stdint.h>

#define B_ 2
#define S_ 4096
#define D_ 768
#define H_ 12
#define DH_ 64
#define L_ 2
#define W_ 256
#define G_ 64
#define FF_ 3072
#define C_ 7
#define SEP_ 2
#define NEG_ (-1000000000.0f)
#define NC_ 16

typedef __attribute__((ext_vector_type(8))) short short8;
typedef __attribute__((ext_vector_type(4))) float f32x4;

__device__ __forceinline__ float bfu2f(unsigned short u) {
    return __uint_as_float(((unsigned int)u) << 16);
}
__device__ __forceinline__ unsigned short f2bfu(float f) {
    unsigned int x = __float_as_uint(f);
    unsigned int r = (x + 0x7fffu + ((x >> 16) & 1u)) >> 16;
    return (unsigned short)r;
}
__device__ __forceinline__ float gelu_tanh(float v) {
    float c = 0.7978845608028654f * (v + 0.044715f * v * v * v);
    return 0.5f * v * (1.0f + tanhf(c));
}

// ---------------- weight convert+transpose: src [L][K][N] f32 -> dst [L][N][K] bf16 ----------------
__global__ __launch_bounds__(256) void k_wtrans(
    const float* __restrict__ src, unsigned short* __restrict__ dst,
    int K, int N, size_t dstStride) {
    int l = blockIdx.z;
    src += (size_t)l * K * N;
    dst += (size_t)l * dstStride;
    __shared__ unsigned short tile[32][36];
    int t = threadIdx.x;
    int r = t >> 3, c4 = (t & 7) << 2;
    int k0 = blockIdx.y << 5, n0 = blockIdx.x << 5;
    float4 v = *(const float4*)(src + (size_t)(k0 + r) * N + n0 + c4);
    tile[c4 + 0][r] = f2bfu(v.x);
    tile[c4 + 1][r] = f2bfu(v.y);
    tile[c4 + 2][r] = f2bfu(v.z);
    tile[c4 + 3][r] = f2bfu(v.w);
    __syncthreads();
    ushort4 o;
    o.x = tile[r][c4 + 0]; o.y = tile[r][c4 + 1];
    o.z = tile[r][c4 + 2]; o.w = tile[r][c4 + 3];
    *(ushort4*)(dst + (size_t)(n0 + r) * K + k0 + c4) = o;
}

// ---------------- embedding + LN: one wave per row ----------------
__global__ __launch_bounds__(256) void k_embed_ln(
    const int* __restrict__ ids, const float* __restrict__ etok,
    const float* __restrict__ epos, const float* __restrict__ lns,
    const float* __restrict__ lnb, float* __restrict__ x,
    unsigned short* __restrict__ xb) {
    int row = (blockIdx.x << 2) + (threadIdx.x >> 6);
    int lane = threadIdx.x & 63;
    int s = row & (S_ - 1);
    int id = ids[row];
    const float4* ep = (const float4*)(etok + (size_t)id * D_);
    const float4* pp = (const float4*)(epos + (size_t)s * D_);
    float4 a[3];
    float sum = 0.f, sum2 = 0.f;
#pragma unroll
    for (int i = 0; i < 3; i++) {
        float4 ev = ep[lane + i * 64];
        float4 pv = pp[lane + i * 64];
        ev.x += pv.x; ev.y += pv.y; ev.z += pv.z; ev.w += pv.w;
        a[i] = ev;
        sum  += ev.x + ev.y + ev.z + ev.w;
        sum2 += ev.x * ev.x + ev.y * ev.y + ev.z * ev.z + ev.w * ev.w;
    }
#pragma unroll
    for (int off = 1; off < 64; off <<= 1) {
        sum += __shfl_xor(sum, off);
        sum2 += __shfl_xor(sum2, off);
    }
    float mean = sum * (1.0f / D_);
    float var = sum2 * (1.0f / D_) - mean * mean;
    float rs = rsqrtf(var + 1e-5f);
    float4* xp = (float4*)(x + (size_t)row * D_);
#pragma unroll
    for (int i = 0; i < 3; i++) {
        float4 g = *(const float4*)(lns + lane * 4 + i * 256);
        float4 bb = *(const float4*)(lnb + lane * 4 + i * 256);
        float4 v;
        v.x = (a[i].x - mean) * rs * g.x + bb.x;
        v.y = (a[i].y - mean) * rs * g.y + bb.y;
        v.z = (a[i].z - mean) * rs * g.z + bb.z;
        v.w = (a[i].w - mean) * rs * g.w + bb.w;
        xp[lane + i * 64] = v;
        ushort4 u; u.x = f2bfu(v.x); u.y = f2bfu(v.y); u.z = f2bfu(v.z); u.w = f2bfu(v.w);
        *(ushort4*)(xb + (size_t)row * D_ + lane * 4 + i * 256) = u;
    }
}

// ---------------- residual add + LN (x += y [+ y2]), one wave per row ----------------
__global__ __launch_bounds__(256) void k_add_ln(
    float* __restrict__ x, const float* __restrict__ y, const float* __restrict__ y2,
    const float* __restrict__ lns, const float* __restrict__ lnb,
    unsigned short* __restrict__ xb) {
    int row = (blockIdx.x << 2) + (threadIdx.x >> 6);
    int lane = threadIdx.x & 63;
    float4* xp = (float4*)(x + (size_t)row * D_);
    const float4* yp = (const float4*)(y + (size_t)row * D_);
    const float4* y2p = y2 ? (const float4*)(y2 + (size_t)row * D_) : nullptr;
    float4 a[3];
    float sum = 0.f, sum2 = 0.f;
#pragma unroll
    for (int i = 0; i < 3; i++) {
        float4 xv = xp[lane + i * 64];
        float4 yv = yp[lane + i * 64];
        xv.x += yv.x; xv.y += yv.y; xv.z += yv.z; xv.w += yv.w;
        if (y2p) {
            float4 zv = y2p[lane + i * 64];
            xv.x += zv.x; xv.y += zv.y; xv.z += zv.z; xv.w += zv.w;
        }
        a[i] = xv;
        sum  += xv.x + xv.y + xv.z + xv.w;
        sum2 += xv.x * xv.x + xv.y * xv.y + xv.z * xv.z + xv.w * xv.w;
    }
#pragma unroll
    for (int off = 1; off < 64; off <<= 1) {
        sum += __shfl_xor(sum, off);
        sum2 += __shfl_xor(sum2, off);
    }
    float mean = sum * (1.0f / D_);
    float var = sum2 * (1.0f / D_) - mean * mean;
    float rs = rsqrtf(var + 1e-5f);
#pragma unroll
    for (int i = 0; i < 3; i++) {
        float4 g = *(const float4*)(lns + lane * 4 + i * 256);
        float4 bb = *(const float4*)(lnb + lane * 4 + i * 256);
        float4 v;
        v.x = (a[i].x - mean) * rs * g.x + bb.x;
        v.y = (a[i].y - mean) * rs * g.y + bb.y;
        v.z = (a[i].z - mean) * rs * g.z + bb.z;
        v.w = (a[i].w - mean) * rs * g.w + bb.w;
        xp[lane + i * 64] = v;
        ushort4 u; u.x = f2bfu(v.x); u.y = f2bfu(v.y); u.z = f2bfu(v.z); u.w = f2bfu(v.w);
        *(ushort4*)(xb + (size_t)row * D_ + lane * 4 + i * 256) = u;
    }
}

// ---------------- global-token index extraction ----------------
__global__ __launch_bounds__(256) void k_idx(const int* __restrict__ ids, int* __restrict__ idxg) {
    int b = blockIdx.x;
    int t = threadIdx.x;
    __shared__ int cnt[256];
    __shared__ int totsh;
    int loc[16];
    int n = 0;
#pragma unroll
    for (int i = 0; i < 16; i++) {
        int s = t * 16 + i;
        if (s == 0 || ids[b * S_ + s] == SEP_) loc[n++] = s;
    }
    cnt[t] = n;
    __syncthreads();
    int base = 0;
    for (int u = 0; u < t; u++) base += cnt[u];
    for (int i = 0; i < n; i++) {
        int o = base + i;
        if (o < G_) idxg[b * G_ + o] = loc[i];
    }
    if (t == 255) totsh = base + n;
    __syncthreads();
    if (t == 0)
        for (int o = totsh; o < G_; o++) idxg[b * G_ + o] = 0;
}

// ---------------- MFMA GEMM ----------------
// C[M,N] = A[M,K](bf16) @ W + bias. Weight: Wt bf16 [N][K] if non-null, else Wf f32 [K][N].
// Split-K via gridDim.z: slice 0 -> Cf (+bias), slice 1 -> Cf2 (no bias). act only valid unsplit.
__global__ __launch_bounds__(256) void k_gemm_mfma(
    const unsigned short* __restrict__ A, const unsigned short* __restrict__ Wt,
    const float* __restrict__ Wf, const float* __restrict__ bias,
    float* __restrict__ Cf, float* __restrict__ Cf2, unsigned short* __restrict__ Cb,
    int M, int N, int K, int act) {
    __shared__ unsigned short As[128][40];
    __shared__ unsigned short Bs[128][40];
    int t = threadIdx.x;
    int wave = t >> 6, lane = t & 63, l16 = lane & 15, quad = lane >> 4;
    int m0 = blockIdx.y << 7, n0 = blockIdx.x << 7;
    int wm = (wave >> 1) << 6, wn = (wave & 1) << 6;
    int slice = blockIdx.z;
    int kper = K / gridDim.z;
    int kbeg = slice * kper, kend = kbeg + kper;
    f32x4 acc[4][4];
#pragma unroll
    for (int i = 0; i < 4; i++)
#pragma unroll
        for (int j = 0; j < 4; j++) acc[i][j] = (f32x4){0.f, 0.f, 0.f, 0.f};

    int ar = t >> 1, akc = (t & 1) << 4;
    int bn = t & 127, bkh = (t >> 7) << 4;

    for (int k0 = kbeg; k0 < kend; k0 += 32) {
        const unsigned short* ap = A + (size_t)(m0 + ar) * K + k0 + akc;
        *(uint4*)&As[ar][akc] = *(const uint4*)ap;
        *(uint4*)&As[ar][akc + 8] = *(const uint4*)(ap + 8);
        if (Wt) {
            const unsigned short* bp = Wt + (size_t)(n0 + bn) * K + k0 + bkh;
            *(uint4*)&Bs[bn][bkh] = *(const uint4*)bp;
            *(uint4*)&Bs[bn][bkh + 8] = *(const uint4*)(bp + 8);
        } else {
            const float* bp = Wf + (size_t)(k0 + bkh) * N + n0 + bn;
            unsigned int pk[8];
#pragma unroll
            for (int i = 0; i < 8; i++) {
                unsigned int lo = f2bfu(bp[(size_t)(2 * i) * N]);
                unsigned int hi = f2bfu(bp[(size_t)(2 * i + 1) * N]);
                pk[i] = lo | (hi << 16);
            }
            *(uint4*)&Bs[bn][bkh] = *(uint4*)&pk[0];
            *(uint4*)&Bs[bn][bkh + 8] = *(uint4*)&pk[4];
        }
        __syncthreads();
        short8 af[4], bf[4];
#pragma unroll
        for (int i = 0; i < 4; i++) af[i] = *(const short8*)&As[wm + i * 16 + l16][quad * 8];
#pragma unroll
        for (int j = 0; j < 4; j++) bf[j] = *(const short8*)&Bs[wn + j * 16 + l16][quad * 8];
#pragma unroll
        for (int i = 0; i < 4; i++)
#pragma unroll
            for (int j = 0; j < 4; j++)
                acc[i][j] = __builtin_amdgcn_mfma_f32_16x16x32_bf16(af[i], bf[j], acc[i][j], 0, 0, 0);
        __syncthreads();
    }
    float bj[4];
#pragma unroll
    for (int j = 0; j < 4; j++) bj[j] = (slice == 0) ? bias[n0 + wn + j * 16 + l16] : 0.f;
    float* outp = (slice == 0) ? Cf : Cf2;
#pragma unroll
    for (int i = 0; i < 4; i++)
#pragma unroll
        for (int j = 0; j < 4; j++) {
            int col = n0 + wn + j * 16 + l16;
#pragma unroll
            for (int r = 0; r < 4; r++) {
                int row = m0 + wm + i * 16 + quad * 4 + r;
                float v = acc[i][j][r] + bj[j];
                if (act) v = gelu_tanh(v);
                if (outp) outp[(size_t)row * N + col] = v;
                else      Cb[(size_t)row * N + col] = f2bfu(v);
            }
        }
}

// ---------------- fused 5-way projection GEMM (q,k,v,kg,vg), head-major bf16 out ----------------
struct P5 {
    const unsigned short* Wt[5];
    const float* Wf[5];
    const float* bias[5];
    unsigned short* out[5];
};
__global__ __launch_bounds__(256) void k_gemm_qkv5(
    const unsigned short* __restrict__ A, P5 p) {
    __shared__ unsigned short As[128][40];
    __shared__ unsigned short Bs[128][40];
    const unsigned short* __restrict__ Wt = p.Wt[blockIdx.z];
    const float* __restrict__ Wf = p.Wf[blockIdx.z];
    const float* __restrict__ bias = p.bias[blockIdx.z];
    unsigned short* __restrict__ Cb = p.out[blockIdx.z];
    const int N = D_, K = D_;
    int t = threadIdx.x;
    int wave = t >> 6, lane = t & 63, l16 = lane & 15, quad = lane >> 4;
    int m0 = blockIdx.y << 7, n0 = blockIdx.x << 7;
    int wm = (wave >> 1) << 6, wn = (wave & 1) << 6;
    f32x4 acc[4][4];
#pragma unroll
    for (int i = 0; i < 4; i++)
#pragma unroll
        for (int j = 0; j < 4; j++) acc[i][j] = (f32x4){0.f, 0.f, 0.f, 0.f};

    int ar = t >> 1, akc = (t & 1) << 4;
    int bn = t & 127, bkh = (t >> 7) << 4;

    for (int k0 = 0; k0 < K; k0 += 32) {
        const unsigned short* ap = A + (size_t)(m0 + ar) * K + k0 + akc;
        *(uint4*)&As[ar][akc] = *(const uint4*)ap;
        *(uint4*)&As[ar][akc + 8] = *(const uint4*)(ap + 8);
        if (Wt) {
            const unsigned short* bp = Wt + (size_t)(n0 + bn) * K + k0 + bkh;
            *(uint4*)&Bs[bn][bkh] = *(const uint4*)bp;
            *(uint4*)&Bs[bn][bkh + 8] = *(const uint4*)(bp + 8);
        } else {
            const float* bp = Wf + (size_t)(k0 + bkh) * N + n0 + bn;
            unsigned int pk[8];
#pragma unroll
            for (int i = 0; i < 8; i++) {
                unsigned int lo = f2bfu(bp[(size_t)(2 * i) * N]);
                unsigned int hi = f2bfu(bp[(size_t)(2 * i + 1) * N]);
                pk[i] = lo | (hi << 16);
            }
            *(uint4*)&Bs[bn][bkh] = *(uint4*)&pk[0];
            *(uint4*)&Bs[bn][bkh + 8] = *(uint4*)&pk[4];
        }
        __syncthreads();
        short8 af[4], bf[4];
#pragma unroll
        for (int i = 0; i < 4; i++) af[i] = *(const short8*)&As[wm + i * 16 + l16][quad * 8];
#pragma unroll
        for (int j = 0; j < 4; j++) bf[j] = *(const short8*)&Bs[wn + j * 16 + l16][quad * 8];
#pragma unroll
        for (int i = 0; i < 4; i++)
#pragma unroll
            for (int j = 0; j < 4; j++)
                acc[i][j] = __builtin_amdgcn_mfma_f32_16x16x32_bf16(af[i], bf[j], acc[i][j], 0, 0, 0);
        __syncthreads();
    }
    float bj[4];
#pragma unroll
    for (int j = 0; j < 4; j++) bj[j] = bias[n0 + wn + j * 16 + l16];
#pragma unroll
    for (int i = 0; i < 4; i++)
#pragma unroll
        for (int j = 0; j < 4; j++) {
            int col = n0 + wn + j * 16 + l16;
#pragma unroll
            for (int r = 0; r < 4; r++) {
                int row = m0 + wm + i * 16 + quad * 4 + r;
                float v = acc[i][j][r] + bj[j];
                size_t adr = ((((size_t)(row >> 12)) * H_ + (col >> 6)) * S_ +
                              (row & (S_ - 1))) * DH_ + (col & 63);
                Cb[adr] = f2bfu(v);
            }
        }
}

// ---------------- MFMA flash local attention ----------------
__global__ __launch_bounds__(256) void k_lattn(
    const unsigned short* __restrict__ q, const unsigned short* __restrict__ k,
    const unsigned short* __restrict__ v, const int* __restrict__ ids,
    const int* __restrict__ am, const int* __restrict__ idxg,
    unsigned short* __restrict__ Tb) {
    int s0 = blockIdx.x << 6, h = blockIdx.y, b = blockIdx.z;
    int t = threadIdx.x;
    int wave = t >> 6, lane = t & 63, l16 = lane & 15, quad = lane >> 4;

    __shared__ unsigned short Ks[64][72];
    __shared__ unsigned short Vt[64][72];
    __shared__ unsigned short Ps[64][72];
    __shared__ unsigned char keyok[64];

    const size_t headbase = (((size_t)b * H_) + h) * S_;
    int qrow = s0 + wave * 16 + l16;
    const unsigned short* qptr = q + (headbase + qrow) * DH_;
    short8 qa0 = *(const short8*)(qptr + quad * 8);
    short8 qa1 = *(const short8*)(qptr + 32 + quad * 8);

    f32x4 O[4];
#pragma unroll
    for (int nf = 0; nf < 4; nf++) O[nf] = (f32x4){0.f, 0.f, 0.f, 0.f};
    float m_run[4] = {-3.4e38f, -3.4e38f, -3.4e38f, -3.4e38f};
    float l_run[4] = {0.f, 0.f, 0.f, 0.f};

    int kbase = s0 - 256;
    int sr = t >> 2, sc = t & 3;

    for (int tile = 0; tile < 10; tile++) {
        int sK, sclamp; bool okf;
        if (tile < 9) {
            sK = kbase + tile * 64 + sr;
            bool inr = (sK >= 0) && (sK < S_);
            sclamp = inr ? sK : 0;
            okf = inr && (am[b * S_ + sclamp] != 0) &&
                  !((ids[b * S_ + sclamp] == SEP_) || (sK == 0));
        } else {
            sK = idxg[b * G_ + sr];
            sclamp = sK; okf = true;
        }
        if (sc == 0) keyok[sr] = okf ? 1 : 0;
        const unsigned short* srcK = k + (headbase + sclamp) * DH_;
        const unsigned short* srcV = v + (headbase + sclamp) * DH_;
        uint4 k0v = *(const uint4*)(srcK + sc * 8);
        uint4 k1v = *(const uint4*)(srcK + (sc + 4) * 8);
        uint4 v0v = *(const uint4*)(srcV + sc * 8);
        uint4 v1v = *(const uint4*)(srcV + (sc + 4) * 8);
        *(uint4*)&Ks[sr][sc * 8] = k0v;
        *(uint4*)&Ks[sr][(sc + 4) * 8] = k1v;
        const unsigned int* vw0 = (const unsigned int*)&v0v;
        const unsigned int* vw1 = (const unsigned int*)&v1v;
#pragma unroll
        for (int i = 0; i < 4; i++) {
            Vt[sc * 8 + 2 * i][sr]      = (unsigned short)(vw0[i] & 0xffff);
            Vt[sc * 8 + 2 * i + 1][sr]  = (unsigned short)(vw0[i] >> 16);
            Vt[(sc + 4) * 8 + 2 * i][sr]     = (unsigned short)(vw1[i] & 0xffff);
            Vt[(sc + 4) * 8 + 2 * i + 1][sr] = (unsigned short)(vw1[i] >> 16);
        }
        __syncthreads();

        f32x4 Sf[4];
#pragma unroll
        for (int nf = 0; nf < 4; nf++) {
            short8 b0 = *(const short8*)&Ks[nf * 16 + l16][quad * 8];
            short8 b1 = *(const short8*)&Ks[nf * 16 + l16][32 + quad * 8];
            f32x4 a = (f32x4){0.f, 0.f, 0.f, 0.f};
            a = __builtin_amdgcn_mfma_f32_16x16x32_bf16(qa0, b0, a, 0, 0, 0);
            a = __builtin_amdgcn_mfma_f32_16x16x32_bf16(qa1, b1, a, 0, 0, 0);
            Sf[nf] = a;
        }
        int ktb = kbase + tile * 64;
        bool kval[4];
#pragma unroll
        for (int nf = 0; nf < 4; nf++) kval[nf] = (tile == 9) || (keyok[nf * 16 + l16] != 0);
        float P_[4][4];
        float mt[4];
#pragma unroll
        for (int r = 0; r < 4; r++) {
            int qs = s0 + wave * 16 + quad * 4 + r;
            float mx = -3.4e38f;
#pragma unroll
            for (int nf = 0; nf < 4; nf++) {
                int ks2 = ktb + nf * 16 + l16;
                bool ok = kval[nf] && ((tile == 9) || (ks2 >= qs - 256 && ks2 <= qs + 256));
                float sv = ok ? Sf[nf][r] * 0.125f : NEG_;
                P_[nf][r] = sv;
                mx = fmaxf(mx, sv);
            }
            mt[r] = mx;
        }
#pragma unroll
        for (int off = 1; off < 16; off <<= 1)
#pragma unroll
            for (int r = 0; r < 4; r++) mt[r] = fmaxf(mt[r], __shfl_xor(mt[r], off));
        float alpha[4], lt[4];
#pragma unroll
        for (int r = 0; r < 4; r++) {
            float mn = fmaxf(m_run[r], mt[r]);
            alpha[r] = __expf(m_run[r] - mn);
            m_run[r] = mn; lt[r] = 0.f;
        }
#pragma unroll
        for (int nf = 0; nf < 4; nf++)
#pragma unroll
            for (int r = 0; r < 4; r++) {
                float p = (P_[nf][r] > -1.0e8f) ? __expf(P_[nf][r] - m_run[r]) : 0.f;
                P_[nf][r] = p; lt[r] += p;
            }
#pragma unroll
        for (int off = 1; off < 16; off <<= 1)
#pragma unroll
            for (int r = 0; r < 4; r++) lt[r] += __shfl_xor(lt[r], off);
#pragma unroll
        for (int r = 0; r < 4; r++) l_run[r] = l_run[r] * alpha[r] + lt[r];
#pragma unroll
        for (int nf = 0; nf < 4; nf++) {
            O[nf][0] *= alpha[0]; O[nf][1] *= alpha[1];
            O[nf][2] *= alpha[2]; O[nf][3] *= alpha[3];
        }
#pragma unroll
        for (int nf = 0; nf < 4; nf++)
#pragma unroll
            for (int r = 0; r < 4; r++)
                Ps[wave * 16 + quad * 4 + r][nf * 16 + l16] = f2bfu(P_[nf][r]);
#pragma unroll
        for (int hh = 0; hh < 2; hh++) {
            short8 pa = *(const short8*)&Ps[wave * 16 + l16][hh * 32 + quad * 8];
#pragma unroll
            for (int nf = 0; nf < 4; nf++) {
                short8 vb8 = *(const short8*)&Vt[nf * 16 + l16][hh * 32 + quad * 8];
                O[nf] = __builtin_amdgcn_mfma_f32_16x16x32_bf16(pa, vb8, O[nf], 0, 0, 0);
            }
        }
        __syncthreads();
    }
#pragma unroll
    for (int r = 0; r < 4; r++) {
        int qs = s0 + wave * 16 + quad * 4 + r;
        float invl = 1.0f / l_run[r];
        size_t base = ((size_t)(b * S_ + qs)) * D_ + h * DH_;
#pragma unroll
        for (int nf = 0; nf < 4; nf++)
            Tb[base + nf * 16 + l16] = f2bfu(O[nf][r] * invl);
    }
}

// ---------------- MFMA global-query attention, pass 1 ----------------
__global__ __launch_bounds__(256) void k_gattn_part(
    const unsigned short* __restrict__ qg, const unsigned short* __restrict__ kga,
    const unsigned short* __restrict__ vga, const int* __restrict__ am,
    float* __restrict__ Opart, float* __restrict__ mbuf, float* __restrict__ lbuf) {
    int c = blockIdx.x, h = blockIdx.y, b = blockIdx.z;
    int t = threadIdx.x;
    int wave = t >> 6, lane = t & 63, l16 = lane & 15, quad = lane >> 4;

    __shared__ unsigned short Ks[64][72];
    __shared__ unsigned short Vt[64][72];
    __shared__ unsigned short Ps[64][72];
    __shared__ unsigned char keyok[64];

    const size_t headbase = (((size_t)b * H_) + h) * S_;
    int grow = wave * 16 + l16;
    const unsigned short* qptr = qg + ((size_t)(b * G_ + grow)) * D_ + h * DH_;
    short8 qa0 = *(const short8*)(qptr + quad * 8);
    short8 qa1 = *(const short8*)(qptr + 32 + quad * 8);

    f32x4 O[4];
#pragma unroll
    for (int nf = 0; nf < 4; nf++) O[nf] = (f32x4){0.f, 0.f, 0.f, 0.f};
    float m_run[4] = {-3.4e38f, -3.4e38f, -3.4e38f, -3.4e38f};
    float l_run[4] = {0.f, 0.f, 0.f, 0.f};

    int kbase = c * 256;
    int sr = t >> 2, sc = t & 3;

    for (int tile = 0; tile < 4; tile++) {
        int sK = kbase + tile * 64 + sr;
        if (sc == 0) keyok[sr] = (am[b * S_ + sK] != 0) ? 1 : 0;
        const unsigned short* srcK = kga + (headbase + sK) * DH_;
        const unsigned short* srcV = vga + (headbase + sK) * DH_;
        uint4 k0v = *(const uint4*)(srcK + sc * 8);
        uint4 k1v = *(const uint4*)(srcK + (sc + 4) * 8);
        uint4 v0v = *(const uint4*)(srcV + sc * 8);
        uint4 v1v = *(const uint4*)(srcV + (sc + 4) * 8);
        *(uint4*)&Ks[sr][sc * 8] = k0v;
        *(uint4*)&Ks[sr][(sc + 4) * 8] = k1v;
        const unsigned int* vw0 = (const unsigned int*)&v0v;
        const unsigned int* vw1 = (const unsigned int*)&v1v;
#pragma unroll
        for (int i = 0; i < 4; i++) {
            Vt[sc * 8 + 2 * i][sr]      = (unsigned short)(vw0[i] & 0xffff);
            Vt[sc * 8 + 2 * i + 1][sr]  = (unsigned short)(vw0[i] >> 16);
            Vt[(sc + 4) * 8 + 2 * i][sr]     = (unsigned short)(vw1[i] & 0xffff);
            Vt[(sc + 4) * 8 + 2 * i + 1][sr] = (unsigned short)(vw1[i] >> 16);
        }
        __syncthreads();

        f32x4 Sf[4];
#pragma unroll
        for (int nf = 0; nf < 4; nf++) {
            short8 b0 = *(const short8*)&Ks[nf * 16 + l16][quad * 8];
            short8 b1 = *(const short8*)&Ks[nf * 16 + l16][32 + quad * 8];
            f32x4 a = (f32x4){0.f, 0.f, 0.f, 0.f};
            a = __builtin_amdgcn_mfma_f32_16x16x32_bf16(qa0, b0, a, 0, 0, 0);
            a = __builtin_amdgcn_mfma_f32_16x16x32_bf16(qa1, b1, a, 0, 0, 0);
            Sf[nf] = a;
        }
        bool kval[4];
#pragma unroll
        for (int nf = 0; nf < 4; nf++) kval[nf] = (keyok[nf * 16 + l16] != 0);
        float P_[4][4];
        float mt[4];
#pragma unroll
        for (int r = 0; r < 4; r++) {
            float mx = -3.4e38f;
#pragma unroll
            for (int nf = 0; nf < 4; nf++) {
                float sv = kval[nf] ? Sf[nf][r] * 0.125f : NEG_;
                P_[nf][r] = sv;
                mx = fmaxf(mx, sv);
            }
            mt[r] = mx;
        }
#pragma unroll
        for (int off = 1; off < 16; off <<= 1)
#pragma unroll
            for (int r = 0; r < 4; r++) mt[r] = fmaxf(mt[r], __shfl_xor(mt[r], off));
        float alpha[4], lt[4];
#pragma unroll
        for (int r = 0; r < 4; r++) {
            float mn = fmaxf(m_run[r], mt[r]);
            alpha[r] = __expf(m_run[r] - mn);
            m_run[r] = mn; lt[r] = 0.f;
        }
#pragma unroll
        for (int nf = 0; nf < 4; nf++)
#pragma unroll
            for (int r = 0; r < 4; r++) {
                float p = (P_[nf][r] > -1.0e8f) ? __expf(P_[nf][r] - m_run[r]) : 0.f;
                P_[nf][r] = p; lt[r] += p;
            }
#pragma unroll
        for (int off = 1; off < 16; off <<= 1)
#pragma unroll
            for (int r = 0; r < 4; r++) lt[r] += __shfl_xor(lt[r], off);
#pragma unroll
        for (int r = 0; r < 4; r++) l_run[r] = l_run[r] * alpha[r] + lt[r];
#pragma unroll
        for (int nf = 0; nf < 4; nf++) {
            O[nf][0] *= alpha[0]; O[nf][1] *= alpha[1];
            O[nf][2] *= alpha[2]; O[nf][3] *= alpha[3];
        }
#pragma unroll
        for (int nf = 0; nf < 4; nf++)
#pragma unroll
            for (int r = 0; r < 4; r++)
                Ps[wave * 16 + quad * 4 + r][nf * 16 + l16] = f2bfu(P_[nf][r]);
#pragma unroll
        for (int hh = 0; hh < 2; hh++) {
            short8 pa = *(const short8*)&Ps[wave * 16 + l16][hh * 32 + quad * 8];
#pragma unroll
            for (int nf = 0; nf < 4; nf++) {
                short8 vb8 = *(const short8*)&Vt[nf * 16 + l16][hh * 32 + quad * 8];
                O[nf] = __builtin_amdgcn_mfma_f32_16x16x32_bf16(pa, vb8, O[nf], 0, 0, 0);
            }
        }
        __syncthreads();
    }
    size_t bhc = ((size_t)(b * H_ + h)) * NC_ + c;
#pragma unroll
    for (int r = 0; r < 4; r++) {
        int row = wave * 16 + quad * 4 + r;
#pragma unroll
        for (int nf = 0; nf < 4; nf++)
            Opart[bhc * (G_ * DH_) + (size_t)row * DH_ + nf * 16 + l16] = O[nf][r];
        if (l16 == 0) {
            mbuf[bhc * G_ + row] = m_run[r];
            lbuf[bhc * G_ + row] = l_run[r];
        }
    }
}

// ---------------- global attention pass 2 ----------------
__global__ __launch_bounds__(64) void k_gattn_comb(
    const float* __restrict__ Opart, const float* __restrict__ mbuf,
    const float* __restrict__ lbuf, const int* __restrict__ idxg,
    unsigned short* __restrict__ Tb) {
    int g = blockIdx.x, h = blockIdx.y, b = blockIdx.z;
    int d = threadIdx.x;
    size_t bh = (size_t)(b * H_ + h);
    float M = -3.4e38f;
    float mv[NC_];
#pragma unroll
    for (int c = 0; c < NC_; c++) {
        mv[c] = mbuf[(bh * NC_ + c) * G_ + g];
        M = fmaxf(M, mv[c]);
    }
    float L = 0.f, o = 0.f;
#pragma unroll
    for (int c = 0; c < NC_; c++) {
        float e = __expf(mv[c] - M);
        L += lbuf[(bh * NC_ + c) * G_ + g] * e;
        o += Opart[(bh * NC_ + c) * (G_ * DH_) + (size_t)g * DH_ + d] * e;
    }
    int srow = idxg[b * G_ + g];
    Tb[((size_t)(b * S_ + srow)) * D_ + h * DH_ + d] = f2bfu(o / L);
}

// ---------------- VALU GEMM (small M) ----------------
__global__ __launch_bounds__(256) void k_gemm(
    const float* __restrict__ A, const float* __restrict__ Bw,
    const float* __restrict__ bias, float* __restrict__ Cf,
    unsigned short* __restrict__ Cb, int M, int N, int K, int act) {
    __shared__ float As[16][68];
    __shared__ float Bs[16][68];
    int tl = threadIdx.x;
    int tx = tl & 15, ty = tl >> 4;
    int m0 = blockIdx.y << 6, n0 = blockIdx.x << 6;
    float c[4][4] = {{0.f}};
    int arow = tl >> 2, akk = (tl & 3) << 2;
    int bkk = tl >> 4, bcol = (tl & 15) << 2;
    for (int k0 = 0; k0 < K; k0 += 16) {
        float4 a4 = *(const float4*)(A + (size_t)(m0 + arow) * K + k0 + akk);
        As[akk + 0][arow] = a4.x; As[akk + 1][arow] = a4.y;
        As[akk + 2][arow] = a4.z; As[akk + 3][arow] = a4.w;
        float4 b4 = *(const float4*)(Bw + (size_t)(k0 + bkk) * N + n0 + bcol);
        Bs[bkk][bcol + 0] = b4.x; Bs[bkk][bcol + 1] = b4.y;
        Bs[bkk][bcol + 2] = b4.z; Bs[bkk][bcol + 3] = b4.w;
        __syncthreads();
#pragma unroll
        for (int kk = 0; kk < 16; kk++) {
            float4 av = *(const float4*)&As[kk][ty << 2];
            float4 bv = *(const float4*)&Bs[kk][tx << 2];
            float aa[4] = {av.x, av.y, av.z, av.w};
            float bb[4] = {bv.x, bv.y, bv.z, bv.w};
#pragma unroll
            for (int i = 0; i < 4; i++)
#pragma unroll
                for (int j = 0; j < 4; j++) c[i][j] += aa[i] * bb[j];
        }
        __syncthreads();
    }
    float bias4[4];
#pragma unroll
    for (int j = 0; j < 4; j++) bias4[j] = bias[n0 + (tx << 2) + j];
#pragma unroll
    for (int i = 0; i < 4; i++) {
        int mrow = m0 + (ty << 2) + i;
        float v0 = c[i][0] + bias4[0], v1 = c[i][1] + bias4[1];
        float v2 = c[i][2] + bias4[2], v3 = c[i][3] + bias4[3];
        if (act) { v0 = gelu_tanh(v0); v1 = gelu_tanh(v1); v2 = gelu_tanh(v2); v3 = gelu_tanh(v3); }
        if (Cf) {
            float4 o; o.x = v0; o.y = v1; o.z = v2; o.w = v3;
            *(float4*)(Cf + (size_t)mrow * N + n0 + (tx << 2)) = o;
        } else {
            ushort4 o; o.x = f2bfu(v0); o.y = f2bfu(v1); o.z = f2bfu(v2); o.w = f2bfu(v3);
            *(ushort4*)(Cb + (size_t)mrow * N + n0 + (tx << 2)) = o;
        }
    }
}

// ---------------- gather x rows at global indices ----------------
__global__ __launch_bounds__(256) void k_gather_xg(
    const float* __restrict__ x, const int* __restrict__ idxg, float* __restrict__ xg) {
    int bg = blockIdx.x;
    int b = bg / G_;
    int srow = idxg[bg];
    for (int d = threadIdx.x; d < D_; d += 256)
        xg[(size_t)bg * D_ + d] = x[((size_t)(b * S_ + srow)) * D_ + d];
}

// ---------------- classifier ----------------
__global__ __launch_bounds__(256) void k_classifier(
    const float* __restrict__ x, const float* __restrict__ Wc,
    const float* __restrict__ bc, const int* __restrict__ lo_p,
    int rows_pb, float* __restrict__ out) {
    int r = blockIdx.x;
    int b = r / rows_pb, i = r % rows_pb;
    int s = lo_p[0] + i;
    int t = threadIdx.x;
    __shared__ float xr[D_];
    __shared__ float red[256];
    const float* xrow = x + ((size_t)(b * S_ + s)) * D_;
    for (int d = t; d < D_; d += 256) xr[d] = xrow[d];
    __syncthreads();
    for (int c = 0; c < C_; c++) {
        float loc = 0.f;
        for (int d = t; d < D_; d += 256) loc += xr[d] * Wc[d * C_ + c];
        red[t] = loc; __syncthreads();
        for (int o = 128; o; o >>= 1) { if (t < o) red[t] += red[t + o]; __syncthreads(); }
        if (t == 0) out[r * C_ + c] = red[0] + bc[c];
        __syncthreads();
    }
}

extern "C" void kernel_launch(void* const* d_in, const int* in_sizes, int n_in,
                              void* d_out, int out_size, void* d_ws, size_t ws_size,
                              hipStream_t stream) {
    (void)in_sizes; (void)n_in;
    const float* emb_tok = (const float*)d_in[0];
    const float* emb_pos = (const float*)d_in[1];
    const float* ln_e_s = (const float*)d_in[2];
    const float* ln_e_b = (const float*)d_in[3];
    const float* Wq  = (const float*)d_in[4];
    const float* bq  = (const float*)d_in[5];
    const float* Wk  = (const float*)d_in[6];
    const float* bk  = (const float*)d_in[7];
    const float* Wv  = (const float*)d_in[8];
    const float* bv  = (const float*)d_in[9];
    const float* Wqg = (const float*)d_in[10];
    const float* bqg = (const float*)d_in[11];
    const float* Wkg = (const float*)d_in[12];
    const float* bkg = (const float*)d_in[13];
    const float* Wvg = (const float*)d_in[14];
    const float* bvg = (const float*)d_in[15];
    const float* Wo  = (const float*)d_in[16];
    const float* bo  = (const float*)d_in[17];
    const float* ln1_s = (const float*)d_in[18];
    const float* ln1_b = (const float*)d_in[19];
    const float* Wf1 = (const float*)d_in[20];
    const float* bf1 = (const float*)d_in[21];
    const float* Wf2 = (const float*)d_in[22];
    const float* bf2 = (const float*)d_in[23];
    const float* ln2_s = (const float*)d_in[24];
    const float* ln2_b = (const float*)d_in[25];
    const float* Wc  = (const float*)d_in[26];
    const float* bc  = (const float*)d_in[27];
    const int* input_ids = (const int*)d_in[28];
    const int* attn_mask = (const int*)d_in[29];
    const int* lo        = (const int*)d_in[30];

    const size_t SZB = (size_t)B_ * S_ * D_;
    const size_t D2 = (size_t)D_ * D_;
    const size_t PL = 6 * D2 + 2 * (size_t)D_ * FF_;   // bf16 weight elems per layer
    uint8_t* w = (uint8_t*)d_ws;
    float*          x    = (float*)w;
    unsigned short* xb   = (unsigned short*)(w + 4 * SZB);
    float*          P    = (float*)(w + 6 * SZB);
    unsigned short* qb   = (unsigned short*)(w + 10 * SZB);
    unsigned short* kb   = (unsigned short*)(w + 12 * SZB);
    unsigned short* vb   = (unsigned short*)(w + 14 * SZB);
    unsigned short* kgab = (unsigned short*)(w + 16 * SZB);
    unsigned short* vgab = (unsigned short*)(w + 18 * SZB);
    unsigned short* Hb   = (unsigned short*)(w + 10 * SZB);
    unsigned short* Tb   = (unsigned short*)(w + 20 * SZB);
    float* xg = (float*)(w + 22 * SZB);
    unsigned short* qgb = (unsigned short*)(w + 22 * SZB + (size_t)B_ * G_ * D_ * 4);
    int* idxg = (int*)(w + 22 * SZB + (size_t)B_ * G_ * D_ * 4 + (size_t)B_ * G_ * D_ * 2);
    float* Opart = (float*)(w + 23 * SZB);
    float* mbuf  = (float*)(w + 24 * SZB);
    float* lbuf  = mbuf + (size_t)B_ * H_ * NC_ * G_;

    const size_t P2_OFF = 24 * SZB + (1u << 20);
    const size_t WB_OFF = P2_OFF + 4 * SZB;
    const size_t NEED_P2 = WB_OFF;
    const size_t NEED_W = WB_OFF + L_ * PL * 2;
    float* P2 = (float*)(w + P2_OFF);
    unsigned short* wb = (unsigned short*)(w + WB_OFF);
    const int useW = (ws_size >= NEED_W) ? 1 : 0;
    const int useSplit = (ws_size >= NEED_P2) ? 1 : 0;

    const int BS = B_ * S_;

    if (useW) {
        k_wtrans<<<dim3(D_/32, D_/32, L_), 256, 0, stream>>>(Wq,  wb + 0*D2, D_, D_, PL);
        k_wtrans<<<dim3(D_/32, D_/32, L_), 256, 0, stream>>>(Wk,  wb + 1*D2, D_, D_, PL);
        k_wtrans<<<dim3(D_/32, D_/32, L_), 256, 0, stream>>>(Wv,  wb + 2*D2, D_, D_, PL);
        k_wtrans<<<dim3(D_/32, D_/32, L_), 256, 0, stream>>>(Wkg, wb + 3*D2, D_, D_, PL);
        k_wtrans<<<dim3(D_/32, D_/32, L_), 256, 0, stream>>>(Wvg, wb + 4*D2, D_, D_, PL);
        k_wtrans<<<dim3(D_/32, D_/32, L_), 256, 0, stream>>>(Wo,  wb + 5*D2, D_, D_, PL);
        k_wtrans<<<dim3(FF_/32, D_/32, L_), 256, 0, stream>>>(Wf1, wb + 6*D2, D_, FF_, PL);
        k_wtrans<<<dim3(D_/32, FF_/32, L_), 256, 0, stream>>>(Wf2, wb + 6*D2 + (size_t)D_*FF_, FF_, D_, PL);
    }

    k_embed_ln<<<BS / 4, 256, 0, stream>>>(input_ids, emb_tok, emb_pos, ln_e_s, ln_e_b, x, xb);
    k_idx<<<B_, 256, 0, stream>>>(input_ids, idxg);

    dim3 g_d(D_ / 128, BS / 128);                       // (6, 64)
    dim3 g_ds(D_ / 128, BS / 128, useSplit ? 2 : 1);    // split-K variant
    dim3 g_d5(D_ / 128, BS / 128, 5);
    dim3 g_ff(FF_ / 128, BS / 128);                     // (24, 64)
    dim3 g_qg(D_ / 64, (B_ * G_) / 64);

    for (int l = 0; l < L_; l++) {
        const unsigned short* wbl = wb + (size_t)l * PL;
        P5 p5;
        p5.Wf[0] = Wq  + (size_t)l * D2;  p5.bias[0] = bq  + l * D_;  p5.out[0] = qb;
        p5.Wf[1] = Wk  + (size_t)l * D2;  p5.bias[1] = bk  + l * D_;  p5.out[1] = kb;
        p5.Wf[2] = Wv  + (size_t)l * D2;  p5.bias[2] = bv  + l * D_;  p5.out[2] = vb;
        p5.Wf[3] = Wkg + (size_t)l * D2;  p5.bias[3] = bkg + l * D_;  p5.out[3] = kgab;
        p5.Wf[4] = Wvg + (size_t)l * D2;  p5.bias[4] = bvg + l * D_;  p5.out[4] = vgab;
        for (int i = 0; i < 5; i++) p5.Wt[i] = useW ? (wbl + (size_t)i * D2) : nullptr;
        const float* Wqg_l = Wqg + (size_t)l * D2;
        const float* Wo_l  = Wo  + (size_t)l * D2;
        const float* Wf1_l = Wf1 + (size_t)l * D_ * FF_;
        const float* Wf2_l = Wf2 + (size_t)l * FF_ * D_;
        const unsigned short* Wo_t  = useW ? (wbl + 5 * D2) : nullptr;
        const unsigned short* Wf1_t = useW ? (wbl + 6 * D2) : nullptr;
        const unsigned short* Wf2_t = useW ? (wbl + 6 * D2 + (size_t)D_ * FF_) : nullptr;

        k_gemm_qkv5<<<g_d5, 256, 0, stream>>>(xb, p5);
        k_lattn<<<dim3(S_ / 64, H_, B_), 256, 0, stream>>>(qb, kb, vb, input_ids, attn_mask, idxg, Tb);
        k_gather_xg<<<B_ * G_, 256, 0, stream>>>(x, idxg, xg);
        k_gemm<<<g_qg, 256, 0, stream>>>(xg, Wqg_l, bqg + l * D_, nullptr, qgb, B_ * G_, D_, D_, 0);
        k_gattn_part<<<dim3(NC_, H_, B_), 256, 0, stream>>>(qgb, kgab, vgab, attn_mask, Opart, mbuf, lbuf);
        k_gattn_comb<<<dim3(G_, H_, B_), 64, 0, stream>>>(Opart, mbuf, lbuf, idxg, Tb);
        k_gemm_mfma<<<g_ds, 256, 0, stream>>>(Tb, Wo_t, Wo_l, bo + l * D_, P, P2, nullptr, BS, D_, D_, 0);
        k_add_ln<<<BS / 4, 256, 0, stream>>>(x, P, useSplit ? P2 : nullptr, ln1_s + l * D_, ln1_b + l * D_, xb);
        k_gemm_mfma<<<g_ff, 256, 0, stream>>>(xb, Wf1_t, Wf1_l, bf1 + l * FF_, nullptr, nullptr, Hb, BS, FF_, D_, 1);
        k_gemm_mfma<<<g_ds, 256, 0, stream>>>(Hb, Wf2_t, Wf2_l, bf2 + l * D_, P, P2, nullptr, BS, D_, FF_, 0);
        k_add_ln<<<BS / 4, 256, 0, stream>>>(x, P, useSplit ? P2 : nullptr, ln2_s + l * D_, ln2_b + l * D_, xb);
    }

    int rows = out_size / C_;
    int rows_pb = rows / B_;
    k_classifier<<<rows, 256, 0, stream>>>(x, Wc, bc, lo, rows_pb, (float*)d_out);
}